// Round 8
// baseline (207.092 us; speedup 1.0000x reference)
//
#include <hip/hip_runtime.h>
#include <hip/hip_bf16.h>
#include <math.h>

// Shapes (fixed): B=8, C=16, R=16, M=N=512. K of both real GEMMs = 1024.
//
// Pipeline (4 kernel launches + 1 tiny memset):
//   memset  : zero 8 per-batch ticket counters (ws is poisoned 0xAA)
//   k_front : [blk 0..767] 32x32 transposes: Wi->A2 bf16, Wj->B5T bf16
//             (*alpha,-im), base->baseT fp32; [blk 768..1279] rank-16
//             factors mi_s/mj_s (fp32). FUSED per-batch Gram/stats: the last
//             mimj block of each batch (device-scope ticket, G16 pattern)
//             computes the exact mean/std of mod_r from 16x16 Grams.
//   k_bmod  : rank-16 outer product + normalize (reads stats) + *baseT -> B2T
//   k_gemm<128,64,true>  : G1X = A2 . B2T^T  (512x1024x1024, 512 blk = 2/CU)
//   k_gemm<64,128,false> : out = CC + G1X . B5T^T (512x512x1024, fp32 out)
//
// GEMM: both operands staged via global_load_lds width=16, lane-linear dst,
// XOR chunk swizzle (frag ds_read_b128 ~2-way = free), double-buffered
// single-barrier K-loop (barrier vmcnt drain overlaps full compute phase).

#define WS_CTR     1280        // 8 uint tickets (memset to 0 each call)
#define WS_STATS   1296
#define WS_MIS     4096        // [8][16][512][2] fp32
#define WS_MJS     135168
#define WS_BASET   266240      // [512][512][2] fp32
#define WS_A2      790528      // 512*1024 bf16
#define WS_B5T     1052672     // 512*1024 bf16
#define WS_G1X     1314816     // 8*512*1024 bf16
#define WS_B2T     3411968     // 8*[1024][512] uint (packed bf16 pair); end 5509120

typedef __attribute__((ext_vector_type(8))) short short8;
typedef __attribute__((ext_vector_type(4))) float f32x4;

__device__ __forceinline__ unsigned short f2bf(float f) {
    unsigned int u = __float_as_uint(f);
    u = (u + 0x7FFFu + ((u >> 16) & 1u)) >> 16;
    return (unsigned short)u;
}
__device__ __forceinline__ unsigned int pack2bf(float a, float b) {
    return (unsigned int)f2bf(a) | ((unsigned int)f2bf(b) << 16);
}
__device__ __forceinline__ void load_lds16(const unsigned short* g, unsigned short* l) {
    __builtin_amdgcn_global_load_lds((const __attribute__((address_space(1))) unsigned int*)g,
                                     (__attribute__((address_space(3))) unsigned int*)l, 16, 0, 0);
}

// ---------------------------------------------------------------------------
// k_front: blocks 0..767 = transposes; 768..1279 = mimj + fused gram/stats.
__global__ void k_front(const float* __restrict__ Wi, const float* __restrict__ Wj,
                        const float* __restrict__ base, const float* __restrict__ rd,
                        const float* __restrict__ x, const float* __restrict__ mt,
                        const float* __restrict__ inv, const float* __restrict__ mod_i,
                        const float* __restrict__ mod_j, float* __restrict__ ws) {
    __shared__ __align__(16) char shmem[16896];   // transposes 8448B; gram 16896B
    __shared__ int ticketS;
    int blk = blockIdx.x;
    int tid = threadIdx.x;
    if (blk < 768) {
        float2(*tile)[33] = (float2(*)[33])shmem;
        int mode = blk >> 8;
        int idx = blk & 255;
        int bx = idx & 15, by = idx >> 4;
        int tx = tid & 31, ty = tid >> 5;
        const float* src = (mode == 0) ? Wi : (mode == 1) ? Wj : base;
        for (int i = 0; i < 4; i++) {
            int rIn = by * 32 + ty + i * 8;
            int cIn = bx * 32 + tx;
            tile[ty + i * 8][tx] = *(const float2*)(src + ((size_t)rIn * 512 + cIn) * 2);
        }
        __syncthreads();
        if (mode == 0) {
            unsigned int* A2u = (unsigned int*)(ws + WS_A2);
            for (int i = 0; i < 4; i++) {
                int rOut = bx * 32 + ty + i * 8;
                int cOut = by * 32 + tx;
                float2 v = tile[tx][ty + i * 8];
                A2u[(size_t)rOut * 512 + cOut] = pack2bf(v.x, v.y);
            }
        } else if (mode == 1) {
            float ar = 0.f, ai = 0.f;
            for (int c = 0; c < 16; c++) { ar -= rd[2 * c]; ai -= rd[2 * c + 1]; }
            unsigned int* B5u = (unsigned int*)(ws + WS_B5T);
            for (int i = 0; i < 4; i++) {
                int rOut = bx * 32 + ty + i * 8;
                int cOut = by * 32 + tx;
                float2 v = tile[tx][ty + i * 8];
                float wr = ar * v.x - ai * v.y;
                float wi = ar * v.y + ai * v.x;
                B5u[(size_t)rOut * 512 + cOut] = pack2bf(wr, -wi);
            }
        } else {
            float* baseT = ws + WS_BASET;
            for (int i = 0; i < 4; i++) {
                int rOut = bx * 32 + ty + i * 8;
                int cOut = by * 32 + tx;
                *(float2*)(baseT + ((size_t)rOut * 512 + cOut) * 2) = tile[tx][ty + i * 8];
            }
        }
        return;
    }

    // ---- mimj portion ----
    float* tb = (float*)shmem;          // 128 floats
    float* deS = (float*)shmem + 128;   // 32 floats
    int blk2 = blk - 768;
    bool isMi = blk2 < 256;
    int id = (isMi ? blk2 : blk2 - 256) * 256 + tid;
    int b = id >> 13, rm = id & 8191;
    if (tid < 128) {
        int k = tid >> 5, l = tid & 31;
        float s = 0.f;
        for (int c = 0; c < 16; c++) s += x[b * 16 + c] * mt[(k * 16 + c) * 32 + l];
        tb[tid] = s;
    }
    __syncthreads();
    if (tid < 16) {
        float i0 = inv[2 * tid], i1 = inv[2 * tid + 1];
        float z0 = tb[32 + 2 * tid], z1 = tb[32 + 2 * tid + 1];
        deS[2 * tid]     = i0 * z0 + i1 * z1;
        deS[2 * tid + 1] = i0 * z1 - i1 * z0;
    }
    __syncthreads();
    if (isMi) {
        float acc0 = 0.f, acc1 = 0.f;
        for (int c = 0; c < 16; c++) {
            const float* p = mod_i + (((size_t)c * 8192) + rm) * 2;
            float A0 = p[0] + tb[2 * c], A1 = p[1] + tb[2 * c + 1];
            float d = deS[2 * c], e = deS[2 * c + 1];
            acc0 += d * A0 - e * A1;
            acc1 += e * A0 + d * A1;
        }
        float* dst = ws + WS_MIS + ((size_t)b * 8192 + rm) * 2;
        dst[0] = acc0; dst[1] = acc1;
    } else {
        float acc0 = 0.f, acc1 = 0.f;
        for (int c = 0; c < 16; c++) {
            const float* p = mod_j + (((size_t)c * 8192) + rm) * 2;
            float A0 = p[0] + tb[64 + 2 * c], A1 = p[1] + tb[64 + 2 * c + 1];
            float z0 = tb[96 + 2 * c], z1 = tb[96 + 2 * c + 1];
            float w0 = -z0 * A0 + z1 * A1;
            float w1 =  z1 * A0 + z0 * A1;
            float i0 = inv[2 * c], i1 = inv[2 * c + 1];
            float den = w0 * w0 + w1 * w1;
            acc0 += (i0 * w0 + i1 * w1) / den;
            acc1 += (i0 * w1 - i1 * w0) / den;
        }
        float* dst = ws + WS_MJS + ((size_t)b * 8192 + rm) * 2;
        dst[0] = acc0; dst[1] = acc1;
    }

    // ---- device-scope ticket: last of this batch's 64 blocks does gram ----
    __threadfence();                               // release mi_s/mj_s writes
    __syncthreads();
    if (tid == 0)
        ticketS = (int)atomicAdd((unsigned int*)(ws + WS_CTR) + b, 1u);
    __syncthreads();
    if (ticketS != 63) return;
    __threadfence();                               // acquire others' writes

    // gram for batch b: 8 chunks of 64 columns (algebra verified R3-R7)
    float2(*Vs)[66] = (float2(*)[66])shmem;                   // 8448 B
    float2(*Us)[66] = (float2(*)[66])(shmem + 8448);          // 8448 B
    int r = tid >> 4, r2 = tid & 15;
    const float2* V = (const float2*)(ws + WS_MIS + (size_t)b * 16384);
    const float2* U = (const float2*)(ws + WS_MJS + (size_t)b * 16384);
    float Svr = 0, Svi = 0, Tvr = 0, Tvi = 0;
    float Sur = 0, Sui = 0, Tur = 0, Tui = 0;
    float ar = 0, ai = 0, br = 0, bi = 0;
    for (int h = 0; h < 8; h++) {
        __syncthreads();
        for (int p = 0; p < 4; p++) {
            int f = tid + p * 256;
            int rr = f >> 6, mm = f & 63;
            Vs[rr][mm] = V[rr * 512 + h * 64 + mm];
            Us[rr][mm] = U[rr * 512 + h * 64 + mm];
        }
        __syncthreads();
        for (int mm = 0; mm < 64; mm++) {
            float2 v1 = Vs[r][mm], v2 = Vs[r2][mm];
            float2 u1 = Us[r][mm], u2 = Us[r2][mm];
            Svr += v1.x * v2.x - v1.y * v2.y;  Svi += v1.x * v2.y + v1.y * v2.x;
            Tvr += v1.x * v2.x + v1.y * v2.y;  Tvi += v1.y * v2.x - v1.x * v2.y;
            Sur += u1.x * u2.x - u1.y * u2.y;  Sui += u1.x * u2.y + u1.y * u2.x;
            Tur += u1.x * u2.x + u1.y * u2.y;  Tui += u1.y * u2.x - u1.x * u2.y;
            if (r2 == 0) { ar += v1.x; ai += v1.y; br += u1.x; bi += u1.y; }
        }
    }
    __syncthreads();
    float* red  = (float*)shmem;           // 256 floats
    float* red2 = (float*)shmem + 256;     // 16 floats
    red[tid] = (Sur * Svr - Sui * Svi) + (Tur * Tvr - Tui * Tvi);
    if (r2 == 0) red2[r] = br * ar - bi * ai;
    __syncthreads();
    for (int s = 128; s > 0; s >>= 1) {
        if (tid < s) red[tid] += red[tid + s];
        __syncthreads();
    }
    if (tid == 0) {
        float msum = 0.f;
        for (int i = 0; i < 16; i++) msum += red2[i];
        double MN = 262144.0;
        double mu = (double)msum / MN;
        double sumsq = 0.5 * (double)red[0];
        double var = (sumsq - MN * mu * mu) / (MN - 1.0);
        if (var < 1e-30) var = 1e-30;
        float* stats = ws + WS_STATS;
        stats[b * 2] = (float)mu;
        stats[b * 2 + 1] = (float)(1.0 / sqrt(var));
    }
}

// ---------------------------------------------------------------------------
// k_bmod: rank-16 outer product + normalization (stats precomputed) + *baseT
// -> B2T bf16 expanded-transposed.
__global__ __launch_bounds__(256) void k_bmod(float* __restrict__ ws) {
    const float* mi_s  = ws + WS_MIS;
    const float* mj_s  = ws + WS_MJS;
    const float* baseT = ws + WS_BASET;
    const float* stats = ws + WS_STATS;
    unsigned int* B2T  = (unsigned int*)(ws + WS_B2T);
    int mt = blockIdx.x, nt = blockIdx.y, b = blockIdx.z;
    __shared__ float Ns[16][128];
    __shared__ float Ms[16][128];
    int tid = threadIdx.x, tx = tid & 15, ty = tid >> 4;
    float mu = stats[b * 2], rstd = stats[b * 2 + 1];
    const float* Nb = mj_s + (size_t)b * 16384;
    const float* Mb = mi_s + (size_t)b * 16384;
    int n0 = nt * 64, m0 = mt * 64;
    for (int i = 0; i < 4; i++) {
        int flat = tid + i * 256;
        int col = flat & 63, r = flat >> 6;
        float2 sa = *(const float2*)(Nb + ((size_t)r * 512 + n0 + col) * 2);
        Ns[r][col * 2] = sa.x; Ns[r][col * 2 + 1] = sa.y;
        float2 sb = *(const float2*)(Mb + ((size_t)r * 512 + m0 + col) * 2);
        Ms[r][col * 2] = sb.x; Ms[r][col * 2 + 1] = sb.y;
    }
    __syncthreads();
    float cr[4][4] = {}, ci[4][4] = {};
    for (int r = 0; r < 16; r++) {
        float nr[4], ni[4], mr[4], mi_[4];
        for (int i = 0; i < 4; i++) { nr[i] = Ns[r][(ty * 4 + i) * 2]; ni[i] = Ns[r][(ty * 4 + i) * 2 + 1]; }
        for (int j = 0; j < 4; j++) { mr[j] = Ms[r][(tx + j * 16) * 2]; mi_[j] = Ms[r][(tx + j * 16) * 2 + 1]; }
        for (int i = 0; i < 4; i++)
            for (int j = 0; j < 4; j++) {
                cr[i][j] += nr[i] * mr[j] - ni[i] * mi_[j];
                ci[i][j] += nr[i] * mi_[j] + ni[i] * mr[j];
            }
    }
    unsigned int* Bb = B2T + (size_t)b * 524288;
    for (int i = 0; i < 4; i++) {
        int n = n0 + ty * 4 + i;
        for (int j = 0; j < 4; j++) {
            int m = m0 + tx + j * 16;
            float2 bs = *(const float2*)(baseT + ((size_t)n * 512 + m) * 2);
            float wr = bs.x * (1.f + (cr[i][j] - mu) * rstd);
            float wi = bs.y * (1.f + ci[i][j]);
            Bb[(size_t)(2 * n) * 512 + m]     = pack2bf(wr, -wi);
            Bb[(size_t)(2 * n + 1) * 512 + m] = pack2bf(wi, wr);
        }
    }
}

// ---------------------------------------------------------------------------
// MFMA GEMM, double-buffered single-barrier K-loop.
template <int TM, int TN, bool OUT_BF16>
__global__ __launch_bounds__(256) void k_gemm(const unsigned short* __restrict__ Aall,
                                              const unsigned short* __restrict__ BTall,
                                              void* __restrict__ Call,
                                              const float* __restrict__ td,
                                              const float* __restrict__ rd,
                                              size_t a_bs, size_t bt_bs, size_t c_bs,
                                              int ngl) {
    constexpr int K = 1024;
    constexpr int NK = K / 64;
    constexpr int IT = TM / 32, JT = TN / 32;
    constexpr int STG = (TM + TN) * 64;            // shorts per stage buffer
    constexpr int SMC = OUT_BF16 ? TM * (TN + 8) : 0;
    constexpr int SMEMN = (2 * STG > SMC) ? 2 * STG : SMC;
    __shared__ __align__(16) unsigned short smem[SMEMN];

    const int tid = threadIdx.x;
    const int b = blockIdx.z;
    const unsigned short* A  = Aall  + (size_t)b * a_bs;
    const unsigned short* BT = BTall + (size_t)b * bt_bs;
    const int mBase = blockIdx.y * TM;
    const int nBase = blockIdx.x * TN;
    const int wave = tid >> 6, lane = tid & 63;
    const int wm = wave >> 1, wn = wave & 1;
    const int l15 = lane & 15, q = lane >> 4;

    f32x4 acc[IT][JT];
    for (int i = 0; i < IT; i++)
        for (int j = 0; j < JT; j++) acc[i][j] = (f32x4)0.f;

    auto stage = [&](int k0, int buf) {
        unsigned short* As = smem + buf * STG;
        unsigned short* Bs = As + TM * 64;
#pragma unroll
        for (int p = 0; p < TM / 32; p++) {
            int flat = tid + p * 256;
            int r = flat >> 3, c = flat & 7;
            int gc = (c ^ (r & 7)) << 3;
            load_lds16(A + (size_t)(mBase + r) * K + k0 + gc, &As[flat << 3]);
        }
#pragma unroll
        for (int p = 0; p < TN / 32; p++) {
            int flat = tid + p * 256;
            int r = flat >> 3, c = flat & 7;
            int gc = (c ^ (r & 7)) << 3;
            load_lds16(BT + (size_t)(nBase + r) * K + k0 + gc, &Bs[flat << 3]);
        }
    };

    stage(0, 0);
    for (int kt = 0; kt < NK; kt++) {
        __syncthreads();     // drains vmcnt: tile kt landed; tile kt+1 loads
                             // issued below overlap this iteration's compute
        if (kt + 1 < NK) stage((kt + 1) * 64, (kt + 1) & 1);
        const unsigned short* As = smem + (kt & 1) * STG;
        const unsigned short* Bs = As + TM * 64;
#pragma unroll
        for (int ks = 0; ks < 2; ks++) {
            short8 af[IT], bfr[JT];
#pragma unroll
            for (int t = 0; t < IT; t++) {
                int ra = wm * (TM / 2) + t * 16 + l15;
                int ja = (ks * 4 + q) ^ (ra & 7);
                af[t] = *(const short8*)&As[ra * 64 + ja * 8];
            }
#pragma unroll
            for (int t = 0; t < JT; t++) {
                int rb = wn * (TN / 2) + t * 16 + l15;
                int jb = (ks * 4 + q) ^ (rb & 7);
                bfr[t] = *(const short8*)&Bs[rb * 64 + jb * 8];
            }
#pragma unroll
            for (int i = 0; i < IT; i++)
#pragma unroll
                for (int j = 0; j < JT; j++)
                    acc[i][j] = __builtin_amdgcn_mfma_f32_16x16x32_bf16(af[i], bfr[j], acc[i][j], 0, 0, 0);
        }
    }

    if constexpr (OUT_BF16) {
        __syncthreads();     // Cs aliases the staging buffers
        unsigned short* Cs = smem;
#pragma unroll
        for (int i = 0; i < IT; i++) {
            int row0 = wm * (TM / 2) + i * 16 + q * 4;
#pragma unroll
            for (int j = 0; j < JT; j++) {
                int col = wn * (TN / 2) + j * 16 + l15;
#pragma unroll
                for (int r = 0; r < 4; r++)
                    Cs[(row0 + r) * (TN + 8) + col] = f2bf(acc[i][j][r]);
            }
        }
        __syncthreads();
        unsigned short* C = (unsigned short*)Call + (size_t)b * c_bs;
#pragma unroll
        for (int p = 0; p < TM * TN / 2048; p++) {
            int flat = tid + p * 256;
            int r = flat / (TN / 8), c = flat % (TN / 8);
            short8 v = *(const short8*)&Cs[r * (TN + 8) + c * 8];
            *(short8*)(C + (size_t)(mBase + r) * ngl + nBase + c * 8) = v;
        }
    } else {
        float CC = 0.f;
        for (int c = 0; c < 16; c++) CC += td[2 * c + 1] * rd[2 * c + 1] - td[2 * c] * rd[2 * c];
        float* C = (float*)Call + (size_t)b * c_bs;
#pragma unroll
        for (int i = 0; i < IT; i++) {
            int row0 = mBase + wm * (TM / 2) + i * 16 + q * 4;
#pragma unroll
            for (int j = 0; j < JT; j++) {
                int col = nBase + wn * (TN / 2) + j * 16 + l15;
#pragma unroll
                for (int r = 0; r < 4; r++)
                    C[(size_t)(row0 + r) * ngl + col] = acc[i][j][r] + CC;
            }
        }
    }
}

// ---------------------------------------------------------------------------
extern "C" void kernel_launch(void* const* d_in, const int* in_sizes, int n_in,
                              void* d_out, int out_size, void* d_ws, size_t ws_size,
                              hipStream_t stream) {
    const float* x    = (const float*)d_in[0];
    const float* Wi   = (const float*)d_in[1];
    const float* Wj   = (const float*)d_in[2];
    const float* base = (const float*)d_in[3];
    const float* td   = (const float*)d_in[6];
    const float* rd   = (const float*)d_in[7];
    const float* modi = (const float*)d_in[8];
    const float* modj = (const float*)d_in[9];
    const float* inv  = (const float*)d_in[10];
    const float* mt   = (const float*)d_in[11];
    float* ws  = (float*)d_ws;
    float* out = (float*)d_out;

    unsigned short* A2  = (unsigned short*)(ws + WS_A2);
    unsigned short* B5T = (unsigned short*)(ws + WS_B5T);
    unsigned short* B2T = (unsigned short*)(ws + WS_B2T);
    unsigned short* G1X = (unsigned short*)(ws + WS_G1X);

    hipMemsetAsync((char*)d_ws + WS_CTR * 4, 0, 64, stream);
    k_front<<<1280, 256, 0, stream>>>(Wi, Wj, base, rd, x, mt, inv, modi, modj, ws);
    k_bmod<<<dim3(8, 8, 8), 256, 0, stream>>>(ws);
    k_gemm<128, 64, true><<<dim3(16, 4, 8), 256, 0, stream>>>(
        A2, B2T, (void*)G1X, td, rd, (size_t)0, (size_t)1048576, (size_t)524288, 1024);
    k_gemm<64, 128, false><<<dim3(4, 8, 8), 256, 0, stream>>>(
        G1X, B5T, (void*)out, td, rd, (size_t)524288, (size_t)0, (size_t)262144, 512);
}

// Round 9
// 157.567 us; speedup vs baseline: 1.3143x; 1.3143x over previous
//
#include <hip/hip_runtime.h>
#include <hip/hip_bf16.h>
#include <math.h>

// Shapes (fixed): B=8, C=16, R=16, M=N=512. K of both real GEMMs = 1024.
//
// Pipeline (4 launches — the serial-dependency minimum):
//   k_front : [blk 0..767] 32x32 transposes: Wi->A2 bf16, Wj->B5T bf16
//             (*alpha,-im), base->baseT fp32. [blk 768..1023] mimj blocks,
//             RESTRUCTURED: each owns 16r x 32m of one batch -> computes
//             mi/mj AND its 16x16 partial Gram in-LDS, writes partials to
//             distinct slots (no atomics/fences/zeroing needed).
//   k_bmod  : inline gram finish (sum 16 chunk partials -> exact mean/std,
//             ddof=1) + rank-16 outer product + normalize + *baseT -> B2T
//   k_gemm<128,64,true>  : G1X = A2 . B2T^T  (512x1024x1024, 512 blk = 2/CU)
//   k_gemm<64,128,false> : out = CC + G1X . B5T^T (512x512x1024, fp32 out)
//
// R8 lesson: __threadfence() (device scope) = L2 writeback/invalidate; 512 of
// them cost ~110 us. NO intra-kernel cross-block handoff — kernel boundaries
// only.
// GEMM: both operands staged via global_load_lds width=16, lane-linear dst,
// XOR chunk swizzle (frag ds_read_b128 ~2-way = free), double-buffered
// single-barrier K-loop.

#define WS_MIS     4096        // [8][16][512][2] fp32
#define WS_MJS     135168
#define WS_BASET   266240      // [512][512][2] fp32
#define WS_A2      790528      // 512*1024 bf16
#define WS_B5T     1052672     // 512*1024 bf16
#define WS_G1X     1314816     // 8*512*1024 bf16
#define WS_B2T     3411968     // 8*[1024][512] uint (packed bf16 pair)
#define WS_GPV     7606272     // [8][256 pair][16 ch][4] fp32 (Svr,Svi,Tvr,Tvi)
#define WS_GPU     7737344     // [8][256 pair][16 ch][4] fp32 (Sur,Sui,Tur,Tui)
#define WS_CSV     7868416     // [8][16 ch][16 r][2] fp32 (ar,ai)
#define WS_CSU     7872512     // [8][16 ch][16 r][2] fp32 (br,bi) ; end 7876608

typedef __attribute__((ext_vector_type(8))) short short8;
typedef __attribute__((ext_vector_type(4))) float f32x4;

__device__ __forceinline__ unsigned short f2bf(float f) {
    unsigned int u = __float_as_uint(f);
    u = (u + 0x7FFFu + ((u >> 16) & 1u)) >> 16;
    return (unsigned short)u;
}
__device__ __forceinline__ unsigned int pack2bf(float a, float b) {
    return (unsigned int)f2bf(a) | ((unsigned int)f2bf(b) << 16);
}
__device__ __forceinline__ void load_lds16(const unsigned short* g, unsigned short* l) {
    __builtin_amdgcn_global_load_lds((const __attribute__((address_space(1))) unsigned int*)g,
                                     (__attribute__((address_space(3))) unsigned int*)l, 16, 0, 0);
}

// ---------------------------------------------------------------------------
// k_front: blocks 0..767 = transposes; 768..1023 = mimj + in-block Gram.
__global__ void k_front(const float* __restrict__ Wi, const float* __restrict__ Wj,
                        const float* __restrict__ base, const float* __restrict__ rd,
                        const float* __restrict__ x, const float* __restrict__ mt,
                        const float* __restrict__ inv, const float* __restrict__ mod_i,
                        const float* __restrict__ mod_j, float* __restrict__ ws) {
    __shared__ __align__(16) char shmem[8448];
    int blk = blockIdx.x;
    int tid = threadIdx.x;
    if (blk < 768) {
        float2(*tile)[33] = (float2(*)[33])shmem;
        int mode = blk >> 8;
        int idx = blk & 255;
        int bx = idx & 15, by = idx >> 4;
        int tx = tid & 31, ty = tid >> 5;
        const float* src = (mode == 0) ? Wi : (mode == 1) ? Wj : base;
        for (int i = 0; i < 4; i++) {
            int rIn = by * 32 + ty + i * 8;
            int cIn = bx * 32 + tx;
            tile[ty + i * 8][tx] = *(const float2*)(src + ((size_t)rIn * 512 + cIn) * 2);
        }
        __syncthreads();
        if (mode == 0) {
            unsigned int* A2u = (unsigned int*)(ws + WS_A2);
            for (int i = 0; i < 4; i++) {
                int rOut = bx * 32 + ty + i * 8;
                int cOut = by * 32 + tx;
                float2 v = tile[tx][ty + i * 8];
                A2u[(size_t)rOut * 512 + cOut] = pack2bf(v.x, v.y);
            }
        } else if (mode == 1) {
            float ar = 0.f, ai = 0.f;
            for (int c = 0; c < 16; c++) { ar -= rd[2 * c]; ai -= rd[2 * c + 1]; }
            unsigned int* B5u = (unsigned int*)(ws + WS_B5T);
            for (int i = 0; i < 4; i++) {
                int rOut = bx * 32 + ty + i * 8;
                int cOut = by * 32 + tx;
                float2 v = tile[tx][ty + i * 8];
                float wr = ar * v.x - ai * v.y;
                float wi = ar * v.y + ai * v.x;
                B5u[(size_t)rOut * 512 + cOut] = pack2bf(wr, -wi);
            }
        } else {
            float* baseT = ws + WS_BASET;
            for (int i = 0; i < 4; i++) {
                int rOut = bx * 32 + ty + i * 8;
                int cOut = by * 32 + tx;
                *(float2*)(baseT + ((size_t)rOut * 512 + cOut) * 2) = tile[tx][ty + i * 8];
            }
        }
        return;
    }

    // ---- mimj + per-block Gram partials ----
    float* tb  = (float*)shmem;                 // [0..128)
    float* deS = (float*)shmem + 128;           // [128..160)
    float2(*Vs)[33] = (float2(*)[33])((float*)shmem + 160);  // 16x33 float2
    int blk2 = blk - 768;                       // [0,256)
    bool isMi = blk2 < 128;
    int idx = isMi ? blk2 : blk2 - 128;         // [0,128)
    int b = idx >> 4, ch = idx & 15;
    int m0 = ch * 32;
    if (tid < 128) {
        int k = tid >> 5, l = tid & 31;
        float s = 0.f;
        for (int c = 0; c < 16; c++) s += x[b * 16 + c] * mt[(k * 16 + c) * 32 + l];
        tb[tid] = s;
    }
    __syncthreads();
    if (tid < 16) {
        float i0 = inv[2 * tid], i1 = inv[2 * tid + 1];
        float z0 = tb[32 + 2 * tid], z1 = tb[32 + 2 * tid + 1];
        deS[2 * tid]     = i0 * z0 + i1 * z1;
        deS[2 * tid + 1] = i0 * z1 - i1 * z0;
    }
    __syncthreads();
    // two points per thread: (r, ml) and (r+8, ml)
    for (int pp = 0; pp < 2; pp++) {
        int p = tid + pp * 256;
        int r = p >> 5, ml = p & 31;
        int rm = r * 512 + m0 + ml;
        float acc0, acc1;
        if (isMi) {
            acc0 = 0.f; acc1 = 0.f;
            for (int c = 0; c < 16; c++) {
                const float* pg = mod_i + (((size_t)c * 8192) + rm) * 2;
                float A0 = pg[0] + tb[2 * c], A1 = pg[1] + tb[2 * c + 1];
                float d = deS[2 * c], e = deS[2 * c + 1];
                acc0 += d * A0 - e * A1;
                acc1 += e * A0 + d * A1;
            }
            float* dst = ws + WS_MIS + ((size_t)b * 8192 + rm) * 2;
            dst[0] = acc0; dst[1] = acc1;
        } else {
            acc0 = 0.f; acc1 = 0.f;
            for (int c = 0; c < 16; c++) {
                const float* pg = mod_j + (((size_t)c * 8192) + rm) * 2;
                float A0 = pg[0] + tb[64 + 2 * c], A1 = pg[1] + tb[64 + 2 * c + 1];
                float z0 = tb[96 + 2 * c], z1 = tb[96 + 2 * c + 1];
                float w0 = -z0 * A0 + z1 * A1;
                float w1 =  z1 * A0 + z0 * A1;
                float i0 = inv[2 * c], i1 = inv[2 * c + 1];
                float den = w0 * w0 + w1 * w1;
                acc0 += (i0 * w0 + i1 * w1) / den;
                acc1 += (i0 * w1 - i1 * w0) / den;
            }
            float* dst = ws + WS_MJS + ((size_t)b * 8192 + rm) * 2;
            dst[0] = acc0; dst[1] = acc1;
        }
        Vs[r][ml] = make_float2(acc0, acc1);
    }
    __syncthreads();
    // in-block 16x16 partial Gram over 32 columns (gram1 algebra, verbatim)
    {
        int r = tid >> 4, r2 = tid & 15;
        float Sr = 0, Si = 0, Tr = 0, Ti = 0;
        float ar = 0, ai = 0;
        for (int mm = 0; mm < 32; mm++) {
            float2 v1 = Vs[r][mm], v2 = Vs[r2][mm];
            Sr += v1.x * v2.x - v1.y * v2.y;  Si += v1.x * v2.y + v1.y * v2.x;
            Tr += v1.x * v2.x + v1.y * v2.y;  Ti += v1.y * v2.x - v1.x * v2.y;
            if (r2 == 0) { ar += v1.x; ai += v1.y; }
        }
        float* gp = ws + (isMi ? WS_GPV : WS_GPU);
        *(float4*)(gp + (((size_t)b * 256 + tid) * 16 + ch) * 4) = make_float4(Sr, Si, Tr, Ti);
        if (r2 == 0) {
            float* cs = ws + (isMi ? WS_CSV : WS_CSU);
            *(float2*)(cs + (((size_t)b * 16 + ch) * 16 + r) * 2) = make_float2(ar, ai);
        }
    }
}

// ---------------------------------------------------------------------------
// k_bmod: inline gram finish (mu, 1/std) + rank-16 outer product + normalize
// + *baseT -> B2T bf16 expanded-transposed.
__global__ __launch_bounds__(256) void k_bmod(float* __restrict__ ws) {
    const float* mi_s  = ws + WS_MIS;
    const float* mj_s  = ws + WS_MJS;
    const float* baseT = ws + WS_BASET;
    unsigned int* B2T  = (unsigned int*)(ws + WS_B2T);
    int mt = blockIdx.x, nt = blockIdx.y, b = blockIdx.z;
    __shared__ float Ns[16][128];
    __shared__ float Ms[16][128];
    __shared__ float red[256];
    __shared__ float red2[16];
    __shared__ float sStat[2];
    int tid = threadIdx.x, tx = tid & 15, ty = tid >> 4;

    // ---- gram finish for batch b (sum 16 chunk partials, then multiply) ----
    {
        float Svr = 0, Svi = 0, Tvr = 0, Tvi = 0;
        float Sur = 0, Sui = 0, Tur = 0, Tui = 0;
        const float4* gv = (const float4*)(ws + WS_GPV + ((size_t)b * 256 + tid) * 64);
        const float4* gu = (const float4*)(ws + WS_GPU + ((size_t)b * 256 + tid) * 64);
        for (int ch = 0; ch < 16; ch++) {
            float4 a0 = gv[ch], a1 = gu[ch];
            Svr += a0.x; Svi += a0.y; Tvr += a0.z; Tvi += a0.w;
            Sur += a1.x; Sui += a1.y; Tur += a1.z; Tui += a1.w;
        }
        red[tid] = (Sur * Svr - Sui * Svi) + (Tur * Tvr - Tui * Tvi);
        if (tid < 16) {
            float ar = 0, ai = 0, br = 0, bi = 0;
            for (int ch = 0; ch < 16; ch++) {
                float2 cv = *(const float2*)(ws + WS_CSV + (((size_t)b * 16 + ch) * 16 + tid) * 2);
                float2 cu = *(const float2*)(ws + WS_CSU + (((size_t)b * 16 + ch) * 16 + tid) * 2);
                ar += cv.x; ai += cv.y; br += cu.x; bi += cu.y;
            }
            red2[tid] = br * ar - bi * ai;
        }
        __syncthreads();
        for (int s = 128; s > 0; s >>= 1) {
            if (tid < s) red[tid] += red[tid + s];
            __syncthreads();
        }
        if (tid == 0) {
            float msum = 0.f;
            for (int i = 0; i < 16; i++) msum += red2[i];
            double MN = 262144.0;
            double mu = (double)msum / MN;
            double sumsq = 0.5 * (double)red[0];
            double var = (sumsq - MN * mu * mu) / (MN - 1.0);
            if (var < 1e-30) var = 1e-30;
            sStat[0] = (float)mu;
            sStat[1] = (float)(1.0 / sqrt(var));
        }
    }

    const float* Nb = mj_s + (size_t)b * 16384;
    const float* Mb = mi_s + (size_t)b * 16384;
    int n0 = nt * 64, m0 = mt * 64;
    for (int i = 0; i < 4; i++) {
        int flat = tid + i * 256;
        int col = flat & 63, r = flat >> 6;
        float2 sa = *(const float2*)(Nb + ((size_t)r * 512 + n0 + col) * 2);
        Ns[r][col * 2] = sa.x; Ns[r][col * 2 + 1] = sa.y;
        float2 sb = *(const float2*)(Mb + ((size_t)r * 512 + m0 + col) * 2);
        Ms[r][col * 2] = sb.x; Ms[r][col * 2 + 1] = sb.y;
    }
    __syncthreads();
    float cr[4][4] = {}, ci[4][4] = {};
    for (int r = 0; r < 16; r++) {
        float nr[4], ni[4], mr[4], mi_[4];
        for (int i = 0; i < 4; i++) { nr[i] = Ns[r][(ty * 4 + i) * 2]; ni[i] = Ns[r][(ty * 4 + i) * 2 + 1]; }
        for (int j = 0; j < 4; j++) { mr[j] = Ms[r][(tx + j * 16) * 2]; mi_[j] = Ms[r][(tx + j * 16) * 2 + 1]; }
        for (int i = 0; i < 4; i++)
            for (int j = 0; j < 4; j++) {
                cr[i][j] += nr[i] * mr[j] - ni[i] * mi_[j];
                ci[i][j] += nr[i] * mi_[j] + ni[i] * mr[j];
            }
    }
    float mu = sStat[0], rstd = sStat[1];
    unsigned int* Bb = B2T + (size_t)b * 524288;
    for (int i = 0; i < 4; i++) {
        int n = n0 + ty * 4 + i;
        for (int j = 0; j < 4; j++) {
            int m = m0 + tx + j * 16;
            float2 bs = *(const float2*)(baseT + ((size_t)n * 512 + m) * 2);
            float wr = bs.x * (1.f + (cr[i][j] - mu) * rstd);
            float wi = bs.y * (1.f + ci[i][j]);
            Bb[(size_t)(2 * n) * 512 + m]     = pack2bf(wr, -wi);
            Bb[(size_t)(2 * n + 1) * 512 + m] = pack2bf(wi, wr);
        }
    }
}

// ---------------------------------------------------------------------------
// MFMA GEMM, double-buffered single-barrier K-loop (R7-proven, unchanged).
template <int TM, int TN, bool OUT_BF16>
__global__ __launch_bounds__(256) void k_gemm(const unsigned short* __restrict__ Aall,
                                              const unsigned short* __restrict__ BTall,
                                              void* __restrict__ Call,
                                              const float* __restrict__ td,
                                              const float* __restrict__ rd,
                                              size_t a_bs, size_t bt_bs, size_t c_bs,
                                              int ngl) {
    constexpr int K = 1024;
    constexpr int NK = K / 64;
    constexpr int IT = TM / 32, JT = TN / 32;
    constexpr int STG = (TM + TN) * 64;
    constexpr int SMC = OUT_BF16 ? TM * (TN + 8) : 0;
    constexpr int SMEMN = (2 * STG > SMC) ? 2 * STG : SMC;
    __shared__ __align__(16) unsigned short smem[SMEMN];

    const int tid = threadIdx.x;
    const int b = blockIdx.z;
    const unsigned short* A  = Aall  + (size_t)b * a_bs;
    const unsigned short* BT = BTall + (size_t)b * bt_bs;
    const int mBase = blockIdx.y * TM;
    const int nBase = blockIdx.x * TN;
    const int wave = tid >> 6, lane = tid & 63;
    const int wm = wave >> 1, wn = wave & 1;
    const int l15 = lane & 15, q = lane >> 4;

    f32x4 acc[IT][JT];
    for (int i = 0; i < IT; i++)
        for (int j = 0; j < JT; j++) acc[i][j] = (f32x4)0.f;

    auto stage = [&](int k0, int buf) {
        unsigned short* As = smem + buf * STG;
        unsigned short* Bs = As + TM * 64;
#pragma unroll
        for (int p = 0; p < TM / 32; p++) {
            int flat = tid + p * 256;
            int r = flat >> 3, c = flat & 7;
            int gc = (c ^ (r & 7)) << 3;
            load_lds16(A + (size_t)(mBase + r) * K + k0 + gc, &As[flat << 3]);
        }
#pragma unroll
        for (int p = 0; p < TN / 32; p++) {
            int flat = tid + p * 256;
            int r = flat >> 3, c = flat & 7;
            int gc = (c ^ (r & 7)) << 3;
            load_lds16(BT + (size_t)(nBase + r) * K + k0 + gc, &Bs[flat << 3]);
        }
    };

    stage(0, 0);
    for (int kt = 0; kt < NK; kt++) {
        __syncthreads();
        if (kt + 1 < NK) stage((kt + 1) * 64, (kt + 1) & 1);
        const unsigned short* As = smem + (kt & 1) * STG;
        const unsigned short* Bs = As + TM * 64;
#pragma unroll
        for (int ks = 0; ks < 2; ks++) {
            short8 af[IT], bfr[JT];
#pragma unroll
            for (int t = 0; t < IT; t++) {
                int ra = wm * (TM / 2) + t * 16 + l15;
                int ja = (ks * 4 + q) ^ (ra & 7);
                af[t] = *(const short8*)&As[ra * 64 + ja * 8];
            }
#pragma unroll
            for (int t = 0; t < JT; t++) {
                int rb = wn * (TN / 2) + t * 16 + l15;
                int jb = (ks * 4 + q) ^ (rb & 7);
                bfr[t] = *(const short8*)&Bs[rb * 64 + jb * 8];
            }
#pragma unroll
            for (int i = 0; i < IT; i++)
#pragma unroll
                for (int j = 0; j < JT; j++)
                    acc[i][j] = __builtin_amdgcn_mfma_f32_16x16x32_bf16(af[i], bfr[j], acc[i][j], 0, 0, 0);
        }
    }

    if constexpr (OUT_BF16) {
        __syncthreads();
        unsigned short* Cs = smem;
#pragma unroll
        for (int i = 0; i < IT; i++) {
            int row0 = wm * (TM / 2) + i * 16 + q * 4;
#pragma unroll
            for (int j = 0; j < JT; j++) {
                int col = wn * (TN / 2) + j * 16 + l15;
#pragma unroll
                for (int r = 0; r < 4; r++)
                    Cs[(row0 + r) * (TN + 8) + col] = f2bf(acc[i][j][r]);
            }
        }
        __syncthreads();
        unsigned short* C = (unsigned short*)Call + (size_t)b * c_bs;
#pragma unroll
        for (int p = 0; p < TM * TN / 2048; p++) {
            int flat = tid + p * 256;
            int r = flat / (TN / 8), c = flat % (TN / 8);
            short8 v = *(const short8*)&Cs[r * (TN + 8) + c * 8];
            *(short8*)(C + (size_t)(mBase + r) * ngl + nBase + c * 8) = v;
        }
    } else {
        float CC = 0.f;
        for (int c = 0; c < 16; c++) CC += td[2 * c + 1] * rd[2 * c + 1] - td[2 * c] * rd[2 * c];
        float* C = (float*)Call + (size_t)b * c_bs;
#pragma unroll
        for (int i = 0; i < IT; i++) {
            int row0 = mBase + wm * (TM / 2) + i * 16 + q * 4;
#pragma unroll
            for (int j = 0; j < JT; j++) {
                int col = nBase + wn * (TN / 2) + j * 16 + l15;
#pragma unroll
                for (int r = 0; r < 4; r++)
                    C[(size_t)(row0 + r) * ngl + col] = acc[i][j][r] + CC;
            }
        }
    }
}

// ---------------------------------------------------------------------------
extern "C" void kernel_launch(void* const* d_in, const int* in_sizes, int n_in,
                              void* d_out, int out_size, void* d_ws, size_t ws_size,
                              hipStream_t stream) {
    const float* x    = (const float*)d_in[0];
    const float* Wi   = (const float*)d_in[1];
    const float* Wj   = (const float*)d_in[2];
    const float* base = (const float*)d_in[3];
    const float* td   = (const float*)d_in[6];
    const float* rd   = (const float*)d_in[7];
    const float* modi = (const float*)d_in[8];
    const float* modj = (const float*)d_in[9];
    const float* inv  = (const float*)d_in[10];
    const float* mt   = (const float*)d_in[11];
    float* ws  = (float*)d_ws;
    float* out = (float*)d_out;

    unsigned short* A2  = (unsigned short*)(ws + WS_A2);
    unsigned short* B5T = (unsigned short*)(ws + WS_B5T);
    unsigned short* B2T = (unsigned short*)(ws + WS_B2T);
    unsigned short* G1X = (unsigned short*)(ws + WS_G1X);

    k_front<<<1024, 256, 0, stream>>>(Wi, Wj, base, rd, x, mt, inv, modi, modj, ws);
    k_bmod<<<dim3(8, 8, 8), 256, 0, stream>>>(ws);
    k_gemm<128, 64, true><<<dim3(16, 4, 8), 256, 0, stream>>>(
        A2, B2T, (void*)G1X, td, rd, (size_t)0, (size_t)1048576, (size_t)524288, 1024);
    k_gemm<64, 128, false><<<dim3(4, 8, 8), 256, 0, stream>>>(
        G1X, B5T, (void*)out, td, rd, (size_t)524288, (size_t)0, (size_t)262144, 512);
}

// Round 10
// 147.838 us; speedup vs baseline: 1.4008x; 1.0658x over previous
//
#include <hip/hip_runtime.h>
#include <hip/hip_bf16.h>
#include <math.h>

// Shapes (fixed): B=8, C=16, R=16, M=N=512. K of both real GEMMs = 1024.
//
// Pipeline (4 launches — the serial-dependency minimum):
//   k_front : [blk 0..767] 32x32 transposes: Wi->A2 bf16, Wj->B5T bf16
//             (*alpha,-im), base->baseT fp32. [blk 768..1023] mimj blocks:
//             each owns 16r x 32m of one batch -> computes mi/mj AND its
//             16x16 partial Gram in-LDS. Partials stored [b][ch][tid][4]
//             (contiguous 4-KB burst per block — R9's [b][tid][ch] scatter
//             caused 45.6 MB of write-allocate traffic; fixed).
//   k_bmod  : inline gram finish (sum 16 chunk partials -> exact mean/std,
//             ddof=1) + rank-16 outer product + normalize + *baseT -> B2T
//   k_gemm<128,64,true>  : G1X = A2 . B2T^T  (512x1024x1024, 512 blk = 2/CU)
//   k_gemm<64,128,false> : out = CC + G1X . B5T^T (512x512x1024, fp32 out)
//
// R8 lesson: __threadfence() (device scope) = L2 writeback; 512 of them cost
// ~110 us. NO intra-kernel cross-block handoff — kernel boundaries only.
// GEMM: both operands staged via global_load_lds width=16, lane-linear dst,
// XOR chunk swizzle (frag ds_read_b128 ~2-way = free), double-buffered
// single-barrier K-loop.

#define WS_MIS     4096        // [8][16][512][2] fp32
#define WS_MJS     135168
#define WS_BASET   266240      // [512][512][2] fp32
#define WS_A2      790528      // 512*1024 bf16
#define WS_B5T     1052672     // 512*1024 bf16
#define WS_G1X     1314816     // 8*512*1024 bf16
#define WS_B2T     3411968     // 8*[1024][512] uint (packed bf16 pair)
#define WS_GPV     7606272     // [8][16 ch][256 pair][4] fp32 (Svr,Svi,Tvr,Tvi)
#define WS_GPU     7737344     // [8][16 ch][256 pair][4] fp32 (Sur,Sui,Tur,Tui)
#define WS_CSV     7868416     // [8][16 ch][16 r][2] fp32 (ar,ai)
#define WS_CSU     7872512     // [8][16 ch][16 r][2] fp32 (br,bi) ; end 7876608

typedef __attribute__((ext_vector_type(8))) short short8;
typedef __attribute__((ext_vector_type(4))) float f32x4;

__device__ __forceinline__ unsigned short f2bf(float f) {
    unsigned int u = __float_as_uint(f);
    u = (u + 0x7FFFu + ((u >> 16) & 1u)) >> 16;
    return (unsigned short)u;
}
__device__ __forceinline__ unsigned int pack2bf(float a, float b) {
    return (unsigned int)f2bf(a) | ((unsigned int)f2bf(b) << 16);
}
__device__ __forceinline__ void load_lds16(const unsigned short* g, unsigned short* l) {
    __builtin_amdgcn_global_load_lds((const __attribute__((address_space(1))) unsigned int*)g,
                                     (__attribute__((address_space(3))) unsigned int*)l, 16, 0, 0);
}

// ---------------------------------------------------------------------------
// k_front: blocks 0..767 = transposes; 768..1023 = mimj + in-block Gram.
__global__ void k_front(const float* __restrict__ Wi, const float* __restrict__ Wj,
                        const float* __restrict__ base, const float* __restrict__ rd,
                        const float* __restrict__ x, const float* __restrict__ mt,
                        const float* __restrict__ inv, const float* __restrict__ mod_i,
                        const float* __restrict__ mod_j, float* __restrict__ ws) {
    __shared__ __align__(16) char shmem[8448];
    int blk = blockIdx.x;
    int tid = threadIdx.x;
    if (blk < 768) {
        float2(*tile)[33] = (float2(*)[33])shmem;
        int mode = blk >> 8;
        int idx = blk & 255;
        int bx = idx & 15, by = idx >> 4;
        int tx = tid & 31, ty = tid >> 5;
        const float* src = (mode == 0) ? Wi : (mode == 1) ? Wj : base;
        for (int i = 0; i < 4; i++) {
            int rIn = by * 32 + ty + i * 8;
            int cIn = bx * 32 + tx;
            tile[ty + i * 8][tx] = *(const float2*)(src + ((size_t)rIn * 512 + cIn) * 2);
        }
        __syncthreads();
        if (mode == 0) {
            unsigned int* A2u = (unsigned int*)(ws + WS_A2);
            for (int i = 0; i < 4; i++) {
                int rOut = bx * 32 + ty + i * 8;
                int cOut = by * 32 + tx;
                float2 v = tile[tx][ty + i * 8];
                A2u[(size_t)rOut * 512 + cOut] = pack2bf(v.x, v.y);
            }
        } else if (mode == 1) {
            float ar = 0.f, ai = 0.f;
            for (int c = 0; c < 16; c++) { ar -= rd[2 * c]; ai -= rd[2 * c + 1]; }
            unsigned int* B5u = (unsigned int*)(ws + WS_B5T);
            for (int i = 0; i < 4; i++) {
                int rOut = bx * 32 + ty + i * 8;
                int cOut = by * 32 + tx;
                float2 v = tile[tx][ty + i * 8];
                float wr = ar * v.x - ai * v.y;
                float wi = ar * v.y + ai * v.x;
                B5u[(size_t)rOut * 512 + cOut] = pack2bf(wr, -wi);
            }
        } else {
            float* baseT = ws + WS_BASET;
            for (int i = 0; i < 4; i++) {
                int rOut = bx * 32 + ty + i * 8;
                int cOut = by * 32 + tx;
                *(float2*)(baseT + ((size_t)rOut * 512 + cOut) * 2) = tile[tx][ty + i * 8];
            }
        }
        return;
    }

    // ---- mimj + per-block Gram partials ----
    float* tb  = (float*)shmem;                 // [0..128)
    float* deS = (float*)shmem + 128;           // [128..160)
    float2(*Vs)[33] = (float2(*)[33])((float*)shmem + 160);  // 16x33 float2
    int blk2 = blk - 768;                       // [0,256)
    bool isMi = blk2 < 128;
    int idx = isMi ? blk2 : blk2 - 128;         // [0,128)
    int b = idx >> 4, ch = idx & 15;
    int m0 = ch * 32;
    if (tid < 128) {
        int k = tid >> 5, l = tid & 31;
        float s = 0.f;
        for (int c = 0; c < 16; c++) s += x[b * 16 + c] * mt[(k * 16 + c) * 32 + l];
        tb[tid] = s;
    }
    __syncthreads();
    if (tid < 16) {
        float i0 = inv[2 * tid], i1 = inv[2 * tid + 1];
        float z0 = tb[32 + 2 * tid], z1 = tb[32 + 2 * tid + 1];
        deS[2 * tid]     = i0 * z0 + i1 * z1;
        deS[2 * tid + 1] = i0 * z1 - i1 * z0;
    }
    __syncthreads();
    // two points per thread: (r, ml) and (r+8, ml)
    for (int pp = 0; pp < 2; pp++) {
        int p = tid + pp * 256;
        int r = p >> 5, ml = p & 31;
        int rm = r * 512 + m0 + ml;
        float acc0, acc1;
        if (isMi) {
            acc0 = 0.f; acc1 = 0.f;
            for (int c = 0; c < 16; c++) {
                const float* pg = mod_i + (((size_t)c * 8192) + rm) * 2;
                float A0 = pg[0] + tb[2 * c], A1 = pg[1] + tb[2 * c + 1];
                float d = deS[2 * c], e = deS[2 * c + 1];
                acc0 += d * A0 - e * A1;
                acc1 += e * A0 + d * A1;
            }
            float* dst = ws + WS_MIS + ((size_t)b * 8192 + rm) * 2;
            dst[0] = acc0; dst[1] = acc1;
        } else {
            acc0 = 0.f; acc1 = 0.f;
            for (int c = 0; c < 16; c++) {
                const float* pg = mod_j + (((size_t)c * 8192) + rm) * 2;
                float A0 = pg[0] + tb[64 + 2 * c], A1 = pg[1] + tb[64 + 2 * c + 1];
                float z0 = tb[96 + 2 * c], z1 = tb[96 + 2 * c + 1];
                float w0 = -z0 * A0 + z1 * A1;
                float w1 =  z1 * A0 + z0 * A1;
                float i0 = inv[2 * c], i1 = inv[2 * c + 1];
                float den = w0 * w0 + w1 * w1;
                acc0 += (i0 * w0 + i1 * w1) / den;
                acc1 += (i0 * w1 - i1 * w0) / den;
            }
            float* dst = ws + WS_MJS + ((size_t)b * 8192 + rm) * 2;
            dst[0] = acc0; dst[1] = acc1;
        }
        Vs[r][ml] = make_float2(acc0, acc1);
    }
    __syncthreads();
    // in-block 16x16 partial Gram over 32 columns (gram1 algebra, verbatim)
    {
        int r = tid >> 4, r2 = tid & 15;
        float Sr = 0, Si = 0, Tr = 0, Ti = 0;
        float ar = 0, ai = 0;
        for (int mm = 0; mm < 32; mm++) {
            float2 v1 = Vs[r][mm], v2 = Vs[r2][mm];
            Sr += v1.x * v2.x - v1.y * v2.y;  Si += v1.x * v2.y + v1.y * v2.x;
            Tr += v1.x * v2.x + v1.y * v2.y;  Ti += v1.y * v2.x - v1.x * v2.y;
            if (r2 == 0) { ar += v1.x; ai += v1.y; }
        }
        // coalesced: [b][ch][tid][4] — one contiguous 4-KB burst per block
        float* gp = ws + (isMi ? WS_GPV : WS_GPU);
        *(float4*)(gp + (((size_t)b * 16 + ch) * 256 + tid) * 4) = make_float4(Sr, Si, Tr, Ti);
        if (r2 == 0) {
            float* cs = ws + (isMi ? WS_CSV : WS_CSU);
            *(float2*)(cs + (((size_t)b * 16 + ch) * 16 + r) * 2) = make_float2(ar, ai);
        }
    }
}

// ---------------------------------------------------------------------------
// k_bmod: inline gram finish (mu, 1/std) + rank-16 outer product + normalize
// + *baseT -> B2T bf16 expanded-transposed.
__global__ __launch_bounds__(256) void k_bmod(float* __restrict__ ws) {
    const float* mi_s  = ws + WS_MIS;
    const float* mj_s  = ws + WS_MJS;
    const float* baseT = ws + WS_BASET;
    unsigned int* B2T  = (unsigned int*)(ws + WS_B2T);
    int mt = blockIdx.x, nt = blockIdx.y, b = blockIdx.z;
    __shared__ float Ns[16][128];
    __shared__ float Ms[16][128];
    __shared__ float red[256];
    __shared__ float red2[16];
    __shared__ float sStat[2];
    int tid = threadIdx.x, tx = tid & 15, ty = tid >> 4;

    // ---- gram finish for batch b (sum 16 chunk partials, then multiply) ----
    {
        float Svr = 0, Svi = 0, Tvr = 0, Tvi = 0;
        float Sur = 0, Sui = 0, Tur = 0, Tui = 0;
        for (int ch = 0; ch < 16; ch++) {
            float4 a0 = *(const float4*)(ws + WS_GPV + (((size_t)b * 16 + ch) * 256 + tid) * 4);
            float4 a1 = *(const float4*)(ws + WS_GPU + (((size_t)b * 16 + ch) * 256 + tid) * 4);
            Svr += a0.x; Svi += a0.y; Tvr += a0.z; Tvi += a0.w;
            Sur += a1.x; Sui += a1.y; Tur += a1.z; Tui += a1.w;
        }
        red[tid] = (Sur * Svr - Sui * Svi) + (Tur * Tvr - Tui * Tvi);
        if (tid < 16) {
            float ar = 0, ai = 0, br = 0, bi = 0;
            for (int ch = 0; ch < 16; ch++) {
                float2 cv = *(const float2*)(ws + WS_CSV + (((size_t)b * 16 + ch) * 16 + tid) * 2);
                float2 cu = *(const float2*)(ws + WS_CSU + (((size_t)b * 16 + ch) * 16 + tid) * 2);
                ar += cv.x; ai += cv.y; br += cu.x; bi += cu.y;
            }
            red2[tid] = br * ar - bi * ai;
        }
        __syncthreads();
        for (int s = 128; s > 0; s >>= 1) {
            if (tid < s) red[tid] += red[tid + s];
            __syncthreads();
        }
        if (tid == 0) {
            float msum = 0.f;
            for (int i = 0; i < 16; i++) msum += red2[i];
            double MN = 262144.0;
            double mu = (double)msum / MN;
            double sumsq = 0.5 * (double)red[0];
            double var = (sumsq - MN * mu * mu) / (MN - 1.0);
            if (var < 1e-30) var = 1e-30;
            sStat[0] = (float)mu;
            sStat[1] = (float)(1.0 / sqrt(var));
        }
    }

    const float* Nb = mj_s + (size_t)b * 16384;
    const float* Mb = mi_s + (size_t)b * 16384;
    int n0 = nt * 64, m0 = mt * 64;
    for (int i = 0; i < 4; i++) {
        int flat = tid + i * 256;
        int col = flat & 63, r = flat >> 6;
        float2 sa = *(const float2*)(Nb + ((size_t)r * 512 + n0 + col) * 2);
        Ns[r][col * 2] = sa.x; Ns[r][col * 2 + 1] = sa.y;
        float2 sb = *(const float2*)(Mb + ((size_t)r * 512 + m0 + col) * 2);
        Ms[r][col * 2] = sb.x; Ms[r][col * 2 + 1] = sb.y;
    }
    __syncthreads();
    float cr[4][4] = {}, ci[4][4] = {};
    for (int r = 0; r < 16; r++) {
        float nr[4], ni[4], mr[4], mi_[4];
        for (int i = 0; i < 4; i++) { nr[i] = Ns[r][(ty * 4 + i) * 2]; ni[i] = Ns[r][(ty * 4 + i) * 2 + 1]; }
        for (int j = 0; j < 4; j++) { mr[j] = Ms[r][(tx + j * 16) * 2]; mi_[j] = Ms[r][(tx + j * 16) * 2 + 1]; }
        for (int i = 0; i < 4; i++)
            for (int j = 0; j < 4; j++) {
                cr[i][j] += nr[i] * mr[j] - ni[i] * mi_[j];
                ci[i][j] += nr[i] * mi_[j] + ni[i] * mr[j];
            }
    }
    float mu = sStat[0], rstd = sStat[1];
    unsigned int* Bb = B2T + (size_t)b * 524288;
    for (int i = 0; i < 4; i++) {
        int n = n0 + ty * 4 + i;
        for (int j = 0; j < 4; j++) {
            int m = m0 + tx + j * 16;
            float2 bs = *(const float2*)(baseT + ((size_t)n * 512 + m) * 2);
            float wr = bs.x * (1.f + (cr[i][j] - mu) * rstd);
            float wi = bs.y * (1.f + ci[i][j]);
            Bb[(size_t)(2 * n) * 512 + m]     = pack2bf(wr, -wi);
            Bb[(size_t)(2 * n + 1) * 512 + m] = pack2bf(wi, wr);
        }
    }
}

// ---------------------------------------------------------------------------
// MFMA GEMM, double-buffered single-barrier K-loop (R7-proven, unchanged).
template <int TM, int TN, bool OUT_BF16>
__global__ __launch_bounds__(256) void k_gemm(const unsigned short* __restrict__ Aall,
                                              const unsigned short* __restrict__ BTall,
                                              void* __restrict__ Call,
                                              const float* __restrict__ td,
                                              const float* __restrict__ rd,
                                              size_t a_bs, size_t bt_bs, size_t c_bs,
                                              int ngl) {
    constexpr int K = 1024;
    constexpr int NK = K / 64;
    constexpr int IT = TM / 32, JT = TN / 32;
    constexpr int STG = (TM + TN) * 64;
    constexpr int SMC = OUT_BF16 ? TM * (TN + 8) : 0;
    constexpr int SMEMN = (2 * STG > SMC) ? 2 * STG : SMC;
    __shared__ __align__(16) unsigned short smem[SMEMN];

    const int tid = threadIdx.x;
    const int b = blockIdx.z;
    const unsigned short* A  = Aall  + (size_t)b * a_bs;
    const unsigned short* BT = BTall + (size_t)b * bt_bs;
    const int mBase = blockIdx.y * TM;
    const int nBase = blockIdx.x * TN;
    const int wave = tid >> 6, lane = tid & 63;
    const int wm = wave >> 1, wn = wave & 1;
    const int l15 = lane & 15, q = lane >> 4;

    f32x4 acc[IT][JT];
    for (int i = 0; i < IT; i++)
        for (int j = 0; j < JT; j++) acc[i][j] = (f32x4)0.f;

    auto stage = [&](int k0, int buf) {
        unsigned short* As = smem + buf * STG;
        unsigned short* Bs = As + TM * 64;
#pragma unroll
        for (int p = 0; p < TM / 32; p++) {
            int flat = tid + p * 256;
            int r = flat >> 3, c = flat & 7;
            int gc = (c ^ (r & 7)) << 3;
            load_lds16(A + (size_t)(mBase + r) * K + k0 + gc, &As[flat << 3]);
        }
#pragma unroll
        for (int p = 0; p < TN / 32; p++) {
            int flat = tid + p * 256;
            int r = flat >> 3, c = flat & 7;
            int gc = (c ^ (r & 7)) << 3;
            load_lds16(BT + (size_t)(nBase + r) * K + k0 + gc, &Bs[flat << 3]);
        }
    };

    stage(0, 0);
    for (int kt = 0; kt < NK; kt++) {
        __syncthreads();
        if (kt + 1 < NK) stage((kt + 1) * 64, (kt + 1) & 1);
        const unsigned short* As = smem + (kt & 1) * STG;
        const unsigned short* Bs = As + TM * 64;
#pragma unroll
        for (int ks = 0; ks < 2; ks++) {
            short8 af[IT], bfr[JT];
#pragma unroll
            for (int t = 0; t < IT; t++) {
                int ra = wm * (TM / 2) + t * 16 + l15;
                int ja = (ks * 4 + q) ^ (ra & 7);
                af[t] = *(const short8*)&As[ra * 64 + ja * 8];
            }
#pragma unroll
            for (int t = 0; t < JT; t++) {
                int rb = wn * (TN / 2) + t * 16 + l15;
                int jb = (ks * 4 + q) ^ (rb & 7);
                bfr[t] = *(const short8*)&Bs[rb * 64 + jb * 8];
            }
#pragma unroll
            for (int i = 0; i < IT; i++)
#pragma unroll
                for (int j = 0; j < JT; j++)
                    acc[i][j] = __builtin_amdgcn_mfma_f32_16x16x32_bf16(af[i], bfr[j], acc[i][j], 0, 0, 0);
        }
    }

    if constexpr (OUT_BF16) {
        __syncthreads();
        unsigned short* Cs = smem;
#pragma unroll
        for (int i = 0; i < IT; i++) {
            int row0 = wm * (TM / 2) + i * 16 + q * 4;
#pragma unroll
            for (int j = 0; j < JT; j++) {
                int col = wn * (TN / 2) + j * 16 + l15;
#pragma unroll
                for (int r = 0; r < 4; r++)
                    Cs[(row0 + r) * (TN + 8) + col] = f2bf(acc[i][j][r]);
            }
        }
        __syncthreads();
        unsigned short* C = (unsigned short*)Call + (size_t)b * c_bs;
#pragma unroll
        for (int p = 0; p < TM * TN / 2048; p++) {
            int flat = tid + p * 256;
            int r = flat / (TN / 8), c = flat % (TN / 8);
            short8 v = *(const short8*)&Cs[r * (TN + 8) + c * 8];
            *(short8*)(C + (size_t)(mBase + r) * ngl + nBase + c * 8) = v;
        }
    } else {
        float CC = 0.f;
        for (int c = 0; c < 16; c++) CC += td[2 * c + 1] * rd[2 * c + 1] - td[2 * c] * rd[2 * c];
        float* C = (float*)Call + (size_t)b * c_bs;
#pragma unroll
        for (int i = 0; i < IT; i++) {
            int row0 = mBase + wm * (TM / 2) + i * 16 + q * 4;
#pragma unroll
            for (int j = 0; j < JT; j++) {
                int col = nBase + wn * (TN / 2) + j * 16 + l15;
#pragma unroll
                for (int r = 0; r < 4; r++)
                    C[(size_t)(row0 + r) * ngl + col] = acc[i][j][r] + CC;
            }
        }
    }
}

// ---------------------------------------------------------------------------
extern "C" void kernel_launch(void* const* d_in, const int* in_sizes, int n_in,
                              void* d_out, int out_size, void* d_ws, size_t ws_size,
                              hipStream_t stream) {
    const float* x    = (const float*)d_in[0];
    const float* Wi   = (const float*)d_in[1];
    const float* Wj   = (const float*)d_in[2];
    const float* base = (const float*)d_in[3];
    const float* td   = (const float*)d_in[6];
    const float* rd   = (const float*)d_in[7];
    const float* modi = (const float*)d_in[8];
    const float* modj = (const float*)d_in[9];
    const float* inv  = (const float*)d_in[10];
    const float* mt   = (const float*)d_in[11];
    float* ws  = (float*)d_ws;
    float* out = (float*)d_out;

    unsigned short* A2  = (unsigned short*)(ws + WS_A2);
    unsigned short* B5T = (unsigned short*)(ws + WS_B5T);
    unsigned short* B2T = (unsigned short*)(ws + WS_B2T);
    unsigned short* G1X = (unsigned short*)(ws + WS_G1X);

    k_front<<<1024, 256, 0, stream>>>(Wi, Wj, base, rd, x, mt, inv, modi, modj, ws);
    k_bmod<<<dim3(8, 8, 8), 256, 0, stream>>>(ws);
    k_gemm<128, 64, true><<<dim3(16, 4, 8), 256, 0, stream>>>(
        A2, B2T, (void*)G1X, td, rd, (size_t)0, (size_t)1048576, (size_t)524288, 1024);
    k_gemm<64, 128, false><<<dim3(4, 8, 8), 256, 0, stream>>>(
        G1X, B5T, (void*)out, td, rd, (size_t)524288, (size_t)0, (size_t)262144, 512);
}

// Round 11
// 147.430 us; speedup vs baseline: 1.4047x; 1.0028x over previous
//
#include <hip/hip_runtime.h>
#include <hip/hip_bf16.h>
#include <math.h>

// Shapes (fixed): B=8, C=16, R=16, M=N=512. K of both real GEMMs = 1024.
//
// Pipeline (4 launches — the serial-dependency minimum):
//   k_front : [blk 0..255] mimj blocks FIRST (heavy: 16r x 32m of one batch,
//             mi/mj + in-block 16x16 partial Gram, partials [b][ch][tid][4]
//             coalesced). [blk 256..767] 32x32 transposes: Wi->A2 bf16,
//             Wj->B5T bf16 (*alpha,-im). base is NOT transposed (R11: bmod
//             reads it directly via an in-LDS 64x64 tile transpose).
//   k_bmod  : inline gram finish (exact mean/std, ddof=1) + rank-16 outer
//             product + normalize + *base(in-LDS transpose) -> B2T bf16
//   k_gemm<128,64,true>  : G1X = A2 . B2T^T  (512x1024x1024, 512 blk = 2/CU)
//   k_gemm<64,128,false> : out = CC + G1X . B5T^T (512x512x1024, fp32 out)
//
// R8 lesson: __threadfence() (device scope) = L2 writeback; 512 of them cost
// ~110 us. NO intra-kernel cross-block handoff — kernel boundaries only.
// R9 lesson: per-thread strided partial writes = write-allocate storm; keep
// block outputs in contiguous bursts.
// GEMM: both operands staged via global_load_lds width=16, lane-linear dst,
// XOR chunk swizzle (frag ds_read_b128 ~2-way = free), double-buffered
// single-barrier K-loop.

#define WS_MIS     4096        // [8][16][512][2] fp32
#define WS_MJS     135168
#define WS_A2      790528      // 512*1024 bf16
#define WS_B5T     1052672     // 512*1024 bf16
#define WS_G1X     1314816     // 8*512*1024 bf16
#define WS_B2T     3411968     // 8*[1024][512] uint (packed bf16 pair)
#define WS_GPV     7606272     // [8][16 ch][256 pair][4] fp32 (Svr,Svi,Tvr,Tvi)
#define WS_GPU     7737344     // [8][16 ch][256 pair][4] fp32 (Sur,Sui,Tur,Tui)
#define WS_CSV     7868416     // [8][16 ch][16 r][2] fp32 (ar,ai)
#define WS_CSU     7872512     // [8][16 ch][16 r][2] fp32 (br,bi) ; end 7876608

typedef __attribute__((ext_vector_type(8))) short short8;
typedef __attribute__((ext_vector_type(4))) float f32x4;

__device__ __forceinline__ unsigned short f2bf(float f) {
    unsigned int u = __float_as_uint(f);
    u = (u + 0x7FFFu + ((u >> 16) & 1u)) >> 16;
    return (unsigned short)u;
}
__device__ __forceinline__ unsigned int pack2bf(float a, float b) {
    return (unsigned int)f2bf(a) | ((unsigned int)f2bf(b) << 16);
}
__device__ __forceinline__ void load_lds16(const unsigned short* g, unsigned short* l) {
    __builtin_amdgcn_global_load_lds((const __attribute__((address_space(1))) unsigned int*)g,
                                     (__attribute__((address_space(3))) unsigned int*)l, 16, 0, 0);
}

// ---------------------------------------------------------------------------
// k_front: blocks 0..255 = mimj + in-block Gram (heavy, dispatched first);
//          blocks 256..767 = Wi/Wj transposes.
__global__ void k_front(const float* __restrict__ Wi, const float* __restrict__ Wj,
                        const float* __restrict__ rd,
                        const float* __restrict__ x, const float* __restrict__ mt,
                        const float* __restrict__ inv, const float* __restrict__ mod_i,
                        const float* __restrict__ mod_j, float* __restrict__ ws) {
    __shared__ __align__(16) char shmem[8448];
    int blk = blockIdx.x;
    int tid = threadIdx.x;
    if (blk >= 256) {
        float2(*tile)[33] = (float2(*)[33])shmem;
        int mode = (blk - 256) >> 8;       // 0: Wi, 1: Wj
        int idx = blk & 255;
        int bx = idx & 15, by = idx >> 4;
        int tx = tid & 31, ty = tid >> 5;
        const float* src = (mode == 0) ? Wi : Wj;
        for (int i = 0; i < 4; i++) {
            int rIn = by * 32 + ty + i * 8;
            int cIn = bx * 32 + tx;
            tile[ty + i * 8][tx] = *(const float2*)(src + ((size_t)rIn * 512 + cIn) * 2);
        }
        __syncthreads();
        if (mode == 0) {
            unsigned int* A2u = (unsigned int*)(ws + WS_A2);
            for (int i = 0; i < 4; i++) {
                int rOut = bx * 32 + ty + i * 8;
                int cOut = by * 32 + tx;
                float2 v = tile[tx][ty + i * 8];
                A2u[(size_t)rOut * 512 + cOut] = pack2bf(v.x, v.y);
            }
        } else {
            float ar = 0.f, ai = 0.f;
            for (int c = 0; c < 16; c++) { ar -= rd[2 * c]; ai -= rd[2 * c + 1]; }
            unsigned int* B5u = (unsigned int*)(ws + WS_B5T);
            for (int i = 0; i < 4; i++) {
                int rOut = bx * 32 + ty + i * 8;
                int cOut = by * 32 + tx;
                float2 v = tile[tx][ty + i * 8];
                float wr = ar * v.x - ai * v.y;
                float wi = ar * v.y + ai * v.x;
                B5u[(size_t)rOut * 512 + cOut] = pack2bf(wr, -wi);
            }
        }
        return;
    }

    // ---- mimj + per-block Gram partials (blocks 0..255, start first) ----
    float* tb  = (float*)shmem;                 // [0..128)
    float* deS = (float*)shmem + 128;           // [128..160)
    float2(*Vs)[33] = (float2(*)[33])((float*)shmem + 160);  // 16x33 float2
    bool isMi = blk < 128;
    int idx = isMi ? blk : blk - 128;           // [0,128)
    int b = idx >> 4, ch = idx & 15;
    int m0 = ch * 32;
    if (tid < 128) {
        int k = tid >> 5, l = tid & 31;
        float s = 0.f;
        for (int c = 0; c < 16; c++) s += x[b * 16 + c] * mt[(k * 16 + c) * 32 + l];
        tb[tid] = s;
    }
    __syncthreads();
    if (tid < 16) {
        float i0 = inv[2 * tid], i1 = inv[2 * tid + 1];
        float z0 = tb[32 + 2 * tid], z1 = tb[32 + 2 * tid + 1];
        deS[2 * tid]     = i0 * z0 + i1 * z1;
        deS[2 * tid + 1] = i0 * z1 - i1 * z0;
    }
    __syncthreads();
    // two points per thread: (r, ml) and (r+8, ml)
    for (int pp = 0; pp < 2; pp++) {
        int p = tid + pp * 256;
        int r = p >> 5, ml = p & 31;
        int rm = r * 512 + m0 + ml;
        float acc0, acc1;
        if (isMi) {
            acc0 = 0.f; acc1 = 0.f;
            for (int c = 0; c < 16; c++) {
                const float* pg = mod_i + (((size_t)c * 8192) + rm) * 2;
                float A0 = pg[0] + tb[2 * c], A1 = pg[1] + tb[2 * c + 1];
                float d = deS[2 * c], e = deS[2 * c + 1];
                acc0 += d * A0 - e * A1;
                acc1 += e * A0 + d * A1;
            }
            float* dst = ws + WS_MIS + ((size_t)b * 8192 + rm) * 2;
            dst[0] = acc0; dst[1] = acc1;
        } else {
            acc0 = 0.f; acc1 = 0.f;
            for (int c = 0; c < 16; c++) {
                const float* pg = mod_j + (((size_t)c * 8192) + rm) * 2;
                float A0 = pg[0] + tb[64 + 2 * c], A1 = pg[1] + tb[64 + 2 * c + 1];
                float z0 = tb[96 + 2 * c], z1 = tb[96 + 2 * c + 1];
                float w0 = -z0 * A0 + z1 * A1;
                float w1 =  z1 * A0 + z0 * A1;
                float i0 = inv[2 * c], i1 = inv[2 * c + 1];
                float den = w0 * w0 + w1 * w1;
                acc0 += (i0 * w0 + i1 * w1) / den;
                acc1 += (i0 * w1 - i1 * w0) / den;
            }
            float* dst = ws + WS_MJS + ((size_t)b * 8192 + rm) * 2;
            dst[0] = acc0; dst[1] = acc1;
        }
        Vs[r][ml] = make_float2(acc0, acc1);
    }
    __syncthreads();
    // in-block 16x16 partial Gram over 32 columns
    {
        int r = tid >> 4, r2 = tid & 15;
        float Sr = 0, Si = 0, Tr = 0, Ti = 0;
        float ar = 0, ai = 0;
        for (int mm = 0; mm < 32; mm++) {
            float2 v1 = Vs[r][mm], v2 = Vs[r2][mm];
            Sr += v1.x * v2.x - v1.y * v2.y;  Si += v1.x * v2.y + v1.y * v2.x;
            Tr += v1.x * v2.x + v1.y * v2.y;  Ti += v1.y * v2.x - v1.x * v2.y;
            if (r2 == 0) { ar += v1.x; ai += v1.y; }
        }
        // coalesced: [b][ch][tid][4] — one contiguous 4-KB burst per block
        float* gp = ws + (isMi ? WS_GPV : WS_GPU);
        *(float4*)(gp + (((size_t)b * 16 + ch) * 256 + tid) * 4) = make_float4(Sr, Si, Tr, Ti);
        if (r2 == 0) {
            float* cs = ws + (isMi ? WS_CSV : WS_CSU);
            *(float2*)(cs + (((size_t)b * 16 + ch) * 16 + r) * 2) = make_float2(ar, ai);
        }
    }
}

// ---------------------------------------------------------------------------
// k_bmod: inline gram finish (mu, 1/std) + rank-16 outer product + normalize
// + *base (read directly, transposed via LDS tile) -> B2T bf16.
__global__ __launch_bounds__(256) void k_bmod(const float* __restrict__ base,
                                              float* __restrict__ ws) {
    const float* mi_s  = ws + WS_MIS;
    const float* mj_s  = ws + WS_MJS;
    unsigned int* B2T  = (unsigned int*)(ws + WS_B2T);
    int mt = blockIdx.x, nt = blockIdx.y, b = blockIdx.z;
    __shared__ float Ns[16][128];
    __shared__ float Ms[16][128];
    __shared__ float2 btile[64][65];     // base[m0+ml][n0+nl] (33.3 KB)
    __shared__ float red[256];
    __shared__ float red2[16];
    __shared__ float sStat[2];
    int tid = threadIdx.x, tx = tid & 15, ty = tid >> 4;
    int n0 = nt * 64, m0 = mt * 64;

    // ---- stage base tile (coalesced rows, transposed on read later) ----
    for (int p = 0; p < 8; p++) {
        int flat = tid + p * 256;
        int row = flat >> 5, colpair = flat & 31;
        const float4 v = *(const float4*)(base + (((size_t)(m0 + row) * 512) + n0 + colpair * 2) * 2);
        btile[row][colpair * 2]     = make_float2(v.x, v.y);
        btile[row][colpair * 2 + 1] = make_float2(v.z, v.w);
    }

    // ---- gram finish for batch b (sum 16 chunk partials, then multiply) ----
    {
        float Svr = 0, Svi = 0, Tvr = 0, Tvi = 0;
        float Sur = 0, Sui = 0, Tur = 0, Tui = 0;
        for (int ch = 0; ch < 16; ch++) {
            float4 a0 = *(const float4*)(ws + WS_GPV + (((size_t)b * 16 + ch) * 256 + tid) * 4);
            float4 a1 = *(const float4*)(ws + WS_GPU + (((size_t)b * 16 + ch) * 256 + tid) * 4);
            Svr += a0.x; Svi += a0.y; Tvr += a0.z; Tvi += a0.w;
            Sur += a1.x; Sui += a1.y; Tur += a1.z; Tui += a1.w;
        }
        red[tid] = (Sur * Svr - Sui * Svi) + (Tur * Tvr - Tui * Tvi);
        if (tid < 16) {
            float ar = 0, ai = 0, br = 0, bi = 0;
            for (int ch = 0; ch < 16; ch++) {
                float2 cv = *(const float2*)(ws + WS_CSV + (((size_t)b * 16 + ch) * 16 + tid) * 2);
                float2 cu = *(const float2*)(ws + WS_CSU + (((size_t)b * 16 + ch) * 16 + tid) * 2);
                ar += cv.x; ai += cv.y; br += cu.x; bi += cu.y;
            }
            red2[tid] = br * ar - bi * ai;
        }
        __syncthreads();
        for (int s = 128; s > 0; s >>= 1) {
            if (tid < s) red[tid] += red[tid + s];
            __syncthreads();
        }
        if (tid == 0) {
            float msum = 0.f;
            for (int i = 0; i < 16; i++) msum += red2[i];
            double MN = 262144.0;
            double mu = (double)msum / MN;
            double sumsq = 0.5 * (double)red[0];
            double var = (sumsq - MN * mu * mu) / (MN - 1.0);
            if (var < 1e-30) var = 1e-30;
            sStat[0] = (float)mu;
            sStat[1] = (float)(1.0 / sqrt(var));
        }
    }

    const float* Nb = mj_s + (size_t)b * 16384;
    const float* Mb = mi_s + (size_t)b * 16384;
    for (int i = 0; i < 4; i++) {
        int flat = tid + i * 256;
        int col = flat & 63, r = flat >> 6;
        float2 sa = *(const float2*)(Nb + ((size_t)r * 512 + n0 + col) * 2);
        Ns[r][col * 2] = sa.x; Ns[r][col * 2 + 1] = sa.y;
        float2 sb = *(const float2*)(Mb + ((size_t)r * 512 + m0 + col) * 2);
        Ms[r][col * 2] = sb.x; Ms[r][col * 2 + 1] = sb.y;
    }
    __syncthreads();
    float cr[4][4] = {}, ci[4][4] = {};
    for (int r = 0; r < 16; r++) {
        float nr[4], ni[4], mr[4], mi_[4];
        for (int i = 0; i < 4; i++) { nr[i] = Ns[r][(ty * 4 + i) * 2]; ni[i] = Ns[r][(ty * 4 + i) * 2 + 1]; }
        for (int j = 0; j < 4; j++) { mr[j] = Ms[r][(tx + j * 16) * 2]; mi_[j] = Ms[r][(tx + j * 16) * 2 + 1]; }
        for (int i = 0; i < 4; i++)
            for (int j = 0; j < 4; j++) {
                cr[i][j] += nr[i] * mr[j] - ni[i] * mi_[j];
                ci[i][j] += nr[i] * mi_[j] + ni[i] * mr[j];
            }
    }
    float mu = sStat[0], rstd = sStat[1];
    unsigned int* Bb = B2T + (size_t)b * 524288;
    for (int i = 0; i < 4; i++) {
        int n = n0 + ty * 4 + i;
        int nl = ty * 4 + i;
        for (int j = 0; j < 4; j++) {
            int m = m0 + tx + j * 16;
            float2 bs = btile[tx + j * 16][nl];     // base[m][n]
            float wr = bs.x * (1.f + (cr[i][j] - mu) * rstd);
            float wi = bs.y * (1.f + ci[i][j]);
            Bb[(size_t)(2 * n) * 512 + m]     = pack2bf(wr, -wi);
            Bb[(size_t)(2 * n + 1) * 512 + m] = pack2bf(wi, wr);
        }
    }
}

// ---------------------------------------------------------------------------
// MFMA GEMM, double-buffered single-barrier K-loop (R7-proven, unchanged).
template <int TM, int TN, bool OUT_BF16>
__global__ __launch_bounds__(256) void k_gemm(const unsigned short* __restrict__ Aall,
                                              const unsigned short* __restrict__ BTall,
                                              void* __restrict__ Call,
                                              const float* __restrict__ td,
                                              const float* __restrict__ rd,
                                              size_t a_bs, size_t bt_bs, size_t c_bs,
                                              int ngl) {
    constexpr int K = 1024;
    constexpr int NK = K / 64;
    constexpr int IT = TM / 32, JT = TN / 32;
    constexpr int STG = (TM + TN) * 64;
    constexpr int SMC = OUT_BF16 ? TM * (TN + 8) : 0;
    constexpr int SMEMN = (2 * STG > SMC) ? 2 * STG : SMC;
    __shared__ __align__(16) unsigned short smem[SMEMN];

    const int tid = threadIdx.x;
    const int b = blockIdx.z;
    const unsigned short* A  = Aall  + (size_t)b * a_bs;
    const unsigned short* BT = BTall + (size_t)b * bt_bs;
    const int mBase = blockIdx.y * TM;
    const int nBase = blockIdx.x * TN;
    const int wave = tid >> 6, lane = tid & 63;
    const int wm = wave >> 1, wn = wave & 1;
    const int l15 = lane & 15, q = lane >> 4;

    f32x4 acc[IT][JT];
    for (int i = 0; i < IT; i++)
        for (int j = 0; j < JT; j++) acc[i][j] = (f32x4)0.f;

    auto stage = [&](int k0, int buf) {
        unsigned short* As = smem + buf * STG;
        unsigned short* Bs = As + TM * 64;
#pragma unroll
        for (int p = 0; p < TM / 32; p++) {
            int flat = tid + p * 256;
            int r = flat >> 3, c = flat & 7;
            int gc = (c ^ (r & 7)) << 3;
            load_lds16(A + (size_t)(mBase + r) * K + k0 + gc, &As[flat << 3]);
        }
#pragma unroll
        for (int p = 0; p < TN / 32; p++) {
            int flat = tid + p * 256;
            int r = flat >> 3, c = flat & 7;
            int gc = (c ^ (r & 7)) << 3;
            load_lds16(BT + (size_t)(nBase + r) * K + k0 + gc, &Bs[flat << 3]);
        }
    };

    stage(0, 0);
    for (int kt = 0; kt < NK; kt++) {
        __syncthreads();
        if (kt + 1 < NK) stage((kt + 1) * 64, (kt + 1) & 1);
        const unsigned short* As = smem + (kt & 1) * STG;
        const unsigned short* Bs = As + TM * 64;
#pragma unroll
        for (int ks = 0; ks < 2; ks++) {
            short8 af[IT], bfr[JT];
#pragma unroll
            for (int t = 0; t < IT; t++) {
                int ra = wm * (TM / 2) + t * 16 + l15;
                int ja = (ks * 4 + q) ^ (ra & 7);
                af[t] = *(const short8*)&As[ra * 64 + ja * 8];
            }
#pragma unroll
            for (int t = 0; t < JT; t++) {
                int rb = wn * (TN / 2) + t * 16 + l15;
                int jb = (ks * 4 + q) ^ (rb & 7);
                bfr[t] = *(const short8*)&Bs[rb * 64 + jb * 8];
            }
#pragma unroll
            for (int i = 0; i < IT; i++)
#pragma unroll
                for (int j = 0; j < JT; j++)
                    acc[i][j] = __builtin_amdgcn_mfma_f32_16x16x32_bf16(af[i], bfr[j], acc[i][j], 0, 0, 0);
        }
    }

    if constexpr (OUT_BF16) {
        __syncthreads();
        unsigned short* Cs = smem;
#pragma unroll
        for (int i = 0; i < IT; i++) {
            int row0 = wm * (TM / 2) + i * 16 + q * 4;
#pragma unroll
            for (int j = 0; j < JT; j++) {
                int col = wn * (TN / 2) + j * 16 + l15;
#pragma unroll
                for (int r = 0; r < 4; r++)
                    Cs[(row0 + r) * (TN + 8) + col] = f2bf(acc[i][j][r]);
            }
        }
        __syncthreads();
        unsigned short* C = (unsigned short*)Call + (size_t)b * c_bs;
#pragma unroll
        for (int p = 0; p < TM * TN / 2048; p++) {
            int flat = tid + p * 256;
            int r = flat / (TN / 8), c = flat % (TN / 8);
            short8 v = *(const short8*)&Cs[r * (TN + 8) + c * 8];
            *(short8*)(C + (size_t)(mBase + r) * ngl + nBase + c * 8) = v;
        }
    } else {
        float CC = 0.f;
        for (int c = 0; c < 16; c++) CC += td[2 * c + 1] * rd[2 * c + 1] - td[2 * c] * rd[2 * c];
        float* C = (float*)Call + (size_t)b * c_bs;
#pragma unroll
        for (int i = 0; i < IT; i++) {
            int row0 = mBase + wm * (TM / 2) + i * 16 + q * 4;
#pragma unroll
            for (int j = 0; j < JT; j++) {
                int col = nBase + wn * (TN / 2) + j * 16 + l15;
#pragma unroll
                for (int r = 0; r < 4; r++)
                    C[(size_t)(row0 + r) * ngl + col] = acc[i][j][r] + CC;
            }
        }
    }
}

// ---------------------------------------------------------------------------
extern "C" void kernel_launch(void* const* d_in, const int* in_sizes, int n_in,
                              void* d_out, int out_size, void* d_ws, size_t ws_size,
                              hipStream_t stream) {
    const float* x    = (const float*)d_in[0];
    const float* Wi   = (const float*)d_in[1];
    const float* Wj   = (const float*)d_in[2];
    const float* base = (const float*)d_in[3];
    const float* td   = (const float*)d_in[6];
    const float* rd   = (const float*)d_in[7];
    const float* modi = (const float*)d_in[8];
    const float* modj = (const float*)d_in[9];
    const float* inv  = (const float*)d_in[10];
    const float* mt   = (const float*)d_in[11];
    float* ws  = (float*)d_ws;
    float* out = (float*)d_out;

    unsigned short* A2  = (unsigned short*)(ws + WS_A2);
    unsigned short* B5T = (unsigned short*)(ws + WS_B5T);
    unsigned short* B2T = (unsigned short*)(ws + WS_B2T);
    unsigned short* G1X = (unsigned short*)(ws + WS_G1X);

    k_front<<<768, 256, 0, stream>>>(Wi, Wj, rd, x, mt, inv, modi, modj, ws);
    k_bmod<<<dim3(8, 8, 8), 256, 0, stream>>>(base, ws);
    k_gemm<128, 64, true><<<dim3(16, 4, 8), 256, 0, stream>>>(
        A2, B2T, (void*)G1X, td, rd, (size_t)0, (size_t)1048576, (size_t)524288, 1024);
    k_gemm<64, 128, false><<<dim3(4, 8, 8), 256, 0, stream>>>(
        G1X, B5T, (void*)out, td, rd, (size_t)524288, (size_t)0, (size_t)262144, 512);
}

// Round 12
// 146.631 us; speedup vs baseline: 1.4123x; 1.0055x over previous
//
#include <hip/hip_runtime.h>
#include <hip/hip_bf16.h>
#include <math.h>

// Shapes (fixed): B=8, C=16, R=16, M=N=512. K of both real GEMMs = 1024.
//
// Pipeline (4 launches — the serial-dependency minimum):
//   k_front : [blk 0..255] mimj blocks (heavy, first): 16r x 32m of one
//             batch, mi/mj + in-block 16x16 partial Gram ([b][ch][tid][4]
//             coalesced). [blk 256..767] 32x32 transposes: Wi->A2 bf16,
//             Wj->B5T bf16 (*alpha,-im). base read directly by bmod.
//   k_bmod  : inline gram finish (exact mean/std, ddof=1) + rank-16 outer
//             product + normalize + *base(in-LDS transpose) -> B2T bf16
//   k_gemm<128,64,true>  : G1X = A2 . B2T^T  (512x1024x1024)
//   k_gemm<64,128,false> : out = CC + G1X . B5T^T (512x512x1024, fp32 out)
//
// R12: XCD-aware grids — batch is the FASTEST grid dim on bmod/gemmA/gemmB.
// MI355X round-robins consecutive linear workgroups over the 8 XCDs, so
// batch b's blocks land on XCD b: per-batch operands (B2T[b], G1X[b]) stay
// in one XCD's 4MB L2 instead of being duplicated into all 8 (R2 counters:
// gemmA FETCH 16.5MB vs 9MB ideal = cross-XCD duplication).
// R8 lesson: NO device-scope fences (L2 writeback storm). R9 lesson: block
// outputs in contiguous bursts (write-allocate).
// GEMM: both operands staged via global_load_lds width=16, lane-linear dst,
// XOR chunk swizzle, double-buffered single-barrier K-loop.

#define WS_MIS     4096        // [8][16][512][2] fp32
#define WS_MJS     135168
#define WS_A2      790528      // 512*1024 bf16
#define WS_B5T     1052672     // 512*1024 bf16
#define WS_G1X     1314816     // 8*512*1024 bf16
#define WS_B2T     3411968     // 8*[1024][512] uint (packed bf16 pair)
#define WS_GPV     7606272     // [8][16 ch][256 pair][4] fp32
#define WS_GPU     7737344     // [8][16 ch][256 pair][4] fp32
#define WS_CSV     7868416     // [8][16 ch][16 r][2] fp32
#define WS_CSU     7872512     // [8][16 ch][16 r][2] fp32 ; end 7876608

typedef __attribute__((ext_vector_type(8))) short short8;
typedef __attribute__((ext_vector_type(4))) float f32x4;

__device__ __forceinline__ unsigned short f2bf(float f) {
    unsigned int u = __float_as_uint(f);
    u = (u + 0x7FFFu + ((u >> 16) & 1u)) >> 16;
    return (unsigned short)u;
}
__device__ __forceinline__ unsigned int pack2bf(float a, float b) {
    return (unsigned int)f2bf(a) | ((unsigned int)f2bf(b) << 16);
}
__device__ __forceinline__ void load_lds16(const unsigned short* g, unsigned short* l) {
    __builtin_amdgcn_global_load_lds((const __attribute__((address_space(1))) unsigned int*)g,
                                     (__attribute__((address_space(3))) unsigned int*)l, 16, 0, 0);
}

// ---------------------------------------------------------------------------
// k_front: blocks 0..255 = mimj + in-block Gram (heavy, dispatched first);
//          blocks 256..767 = Wi/Wj transposes.
__global__ void k_front(const float* __restrict__ Wi, const float* __restrict__ Wj,
                        const float* __restrict__ rd,
                        const float* __restrict__ x, const float* __restrict__ mt,
                        const float* __restrict__ inv, const float* __restrict__ mod_i,
                        const float* __restrict__ mod_j, float* __restrict__ ws) {
    __shared__ __align__(16) char shmem[8448];
    int blk = blockIdx.x;
    int tid = threadIdx.x;
    if (blk >= 256) {
        float2(*tile)[33] = (float2(*)[33])shmem;
        int mode = (blk - 256) >> 8;       // 0: Wi, 1: Wj
        int idx = blk & 255;
        int bx = idx & 15, by = idx >> 4;
        int tx = tid & 31, ty = tid >> 5;
        const float* src = (mode == 0) ? Wi : Wj;
        for (int i = 0; i < 4; i++) {
            int rIn = by * 32 + ty + i * 8;
            int cIn = bx * 32 + tx;
            tile[ty + i * 8][tx] = *(const float2*)(src + ((size_t)rIn * 512 + cIn) * 2);
        }
        __syncthreads();
        if (mode == 0) {
            unsigned int* A2u = (unsigned int*)(ws + WS_A2);
            for (int i = 0; i < 4; i++) {
                int rOut = bx * 32 + ty + i * 8;
                int cOut = by * 32 + tx;
                float2 v = tile[tx][ty + i * 8];
                A2u[(size_t)rOut * 512 + cOut] = pack2bf(v.x, v.y);
            }
        } else {
            float ar = 0.f, ai = 0.f;
            for (int c = 0; c < 16; c++) { ar -= rd[2 * c]; ai -= rd[2 * c + 1]; }
            unsigned int* B5u = (unsigned int*)(ws + WS_B5T);
            for (int i = 0; i < 4; i++) {
                int rOut = bx * 32 + ty + i * 8;
                int cOut = by * 32 + tx;
                float2 v = tile[tx][ty + i * 8];
                float wr = ar * v.x - ai * v.y;
                float wi = ar * v.y + ai * v.x;
                B5u[(size_t)rOut * 512 + cOut] = pack2bf(wr, -wi);
            }
        }
        return;
    }

    // ---- mimj + per-block Gram partials (blocks 0..255, start first) ----
    float* tb  = (float*)shmem;                 // [0..128)
    float* deS = (float*)shmem + 128;           // [128..160)
    float2(*Vs)[33] = (float2(*)[33])((float*)shmem + 160);  // 16x33 float2
    bool isMi = blk < 128;
    int idx = isMi ? blk : blk - 128;           // [0,128)
    int b = idx & 7, ch = idx >> 3;             // batch fastest (XCD spread)
    int m0 = ch * 32;
    if (tid < 128) {
        int k = tid >> 5, l = tid & 31;
        float s = 0.f;
        for (int c = 0; c < 16; c++) s += x[b * 16 + c] * mt[(k * 16 + c) * 32 + l];
        tb[tid] = s;
    }
    __syncthreads();
    if (tid < 16) {
        float i0 = inv[2 * tid], i1 = inv[2 * tid + 1];
        float z0 = tb[32 + 2 * tid], z1 = tb[32 + 2 * tid + 1];
        deS[2 * tid]     = i0 * z0 + i1 * z1;
        deS[2 * tid + 1] = i0 * z1 - i1 * z0;
    }
    __syncthreads();
    for (int pp = 0; pp < 2; pp++) {
        int p = tid + pp * 256;
        int r = p >> 5, ml = p & 31;
        int rm = r * 512 + m0 + ml;
        float acc0, acc1;
        if (isMi) {
            acc0 = 0.f; acc1 = 0.f;
            for (int c = 0; c < 16; c++) {
                const float* pg = mod_i + (((size_t)c * 8192) + rm) * 2;
                float A0 = pg[0] + tb[2 * c], A1 = pg[1] + tb[2 * c + 1];
                float d = deS[2 * c], e = deS[2 * c + 1];
                acc0 += d * A0 - e * A1;
                acc1 += e * A0 + d * A1;
            }
            float* dst = ws + WS_MIS + ((size_t)b * 8192 + rm) * 2;
            dst[0] = acc0; dst[1] = acc1;
        } else {
            acc0 = 0.f; acc1 = 0.f;
            for (int c = 0; c < 16; c++) {
                const float* pg = mod_j + (((size_t)c * 8192) + rm) * 2;
                float A0 = pg[0] + tb[64 + 2 * c], A1 = pg[1] + tb[64 + 2 * c + 1];
                float z0 = tb[96 + 2 * c], z1 = tb[96 + 2 * c + 1];
                float w0 = -z0 * A0 + z1 * A1;
                float w1 =  z1 * A0 + z0 * A1;
                float i0 = inv[2 * c], i1 = inv[2 * c + 1];
                float den = w0 * w0 + w1 * w1;
                acc0 += (i0 * w0 + i1 * w1) / den;
                acc1 += (i0 * w1 - i1 * w0) / den;
            }
            float* dst = ws + WS_MJS + ((size_t)b * 8192 + rm) * 2;
            dst[0] = acc0; dst[1] = acc1;
        }
        Vs[r][ml] = make_float2(acc0, acc1);
    }
    __syncthreads();
    {
        int r = tid >> 4, r2 = tid & 15;
        float Sr = 0, Si = 0, Tr = 0, Ti = 0;
        float ar = 0, ai = 0;
        for (int mm = 0; mm < 32; mm++) {
            float2 v1 = Vs[r][mm], v2 = Vs[r2][mm];
            Sr += v1.x * v2.x - v1.y * v2.y;  Si += v1.x * v2.y + v1.y * v2.x;
            Tr += v1.x * v2.x + v1.y * v2.y;  Ti += v1.y * v2.x - v1.x * v2.y;
            if (r2 == 0) { ar += v1.x; ai += v1.y; }
        }
        float* gp = ws + (isMi ? WS_GPV : WS_GPU);
        *(float4*)(gp + (((size_t)b * 16 + ch) * 256 + tid) * 4) = make_float4(Sr, Si, Tr, Ti);
        if (r2 == 0) {
            float* cs = ws + (isMi ? WS_CSV : WS_CSU);
            *(float2*)(cs + (((size_t)b * 16 + ch) * 16 + r) * 2) = make_float2(ar, ai);
        }
    }
}

// ---------------------------------------------------------------------------
// k_bmod: grid (b=8, t=64): mt = t&7, nt = t>>3. Batch fastest -> XCD-local.
__global__ __launch_bounds__(256) void k_bmod(const float* __restrict__ base,
                                              float* __restrict__ ws) {
    const float* mi_s  = ws + WS_MIS;
    const float* mj_s  = ws + WS_MJS;
    unsigned int* B2T  = (unsigned int*)(ws + WS_B2T);
    int b = blockIdx.x;
    int t = blockIdx.y;
    int mt = t & 7, nt = t >> 3;
    __shared__ float Ns[16][128];
    __shared__ float Ms[16][128];
    __shared__ float2 btile[64][65];
    __shared__ float red[256];
    __shared__ float red2[16];
    __shared__ float sStat[2];
    int tid = threadIdx.x, tx = tid & 15, ty = tid >> 4;
    int n0 = nt * 64, m0 = mt * 64;

    for (int p = 0; p < 8; p++) {
        int flat = tid + p * 256;
        int row = flat >> 5, colpair = flat & 31;
        const float4 v = *(const float4*)(base + (((size_t)(m0 + row) * 512) + n0 + colpair * 2) * 2);
        btile[row][colpair * 2]     = make_float2(v.x, v.y);
        btile[row][colpair * 2 + 1] = make_float2(v.z, v.w);
    }

    {
        float Svr = 0, Svi = 0, Tvr = 0, Tvi = 0;
        float Sur = 0, Sui = 0, Tur = 0, Tui = 0;
        for (int ch = 0; ch < 16; ch++) {
            float4 a0 = *(const float4*)(ws + WS_GPV + (((size_t)b * 16 + ch) * 256 + tid) * 4);
            float4 a1 = *(const float4*)(ws + WS_GPU + (((size_t)b * 16 + ch) * 256 + tid) * 4);
            Svr += a0.x; Svi += a0.y; Tvr += a0.z; Tvi += a0.w;
            Sur += a1.x; Sui += a1.y; Tur += a1.z; Tui += a1.w;
        }
        red[tid] = (Sur * Svr - Sui * Svi) + (Tur * Tvr - Tui * Tvi);
        if (tid < 16) {
            float ar = 0, ai = 0, br = 0, bi = 0;
            for (int ch = 0; ch < 16; ch++) {
                float2 cv = *(const float2*)(ws + WS_CSV + (((size_t)b * 16 + ch) * 16 + tid) * 2);
                float2 cu = *(const float2*)(ws + WS_CSU + (((size_t)b * 16 + ch) * 16 + tid) * 2);
                ar += cv.x; ai += cv.y; br += cu.x; bi += cu.y;
            }
            red2[tid] = br * ar - bi * ai;
        }
        __syncthreads();
        for (int s = 128; s > 0; s >>= 1) {
            if (tid < s) red[tid] += red[tid + s];
            __syncthreads();
        }
        if (tid == 0) {
            float msum = 0.f;
            for (int i = 0; i < 16; i++) msum += red2[i];
            double MN = 262144.0;
            double mu = (double)msum / MN;
            double sumsq = 0.5 * (double)red[0];
            double var = (sumsq - MN * mu * mu) / (MN - 1.0);
            if (var < 1e-30) var = 1e-30;
            sStat[0] = (float)mu;
            sStat[1] = (float)(1.0 / sqrt(var));
        }
    }

    const float* Nb = mj_s + (size_t)b * 16384;
    const float* Mb = mi_s + (size_t)b * 16384;
    for (int i = 0; i < 4; i++) {
        int flat = tid + i * 256;
        int col = flat & 63, r = flat >> 6;
        float2 sa = *(const float2*)(Nb + ((size_t)r * 512 + n0 + col) * 2);
        Ns[r][col * 2] = sa.x; Ns[r][col * 2 + 1] = sa.y;
        float2 sb = *(const float2*)(Mb + ((size_t)r * 512 + m0 + col) * 2);
        Ms[r][col * 2] = sb.x; Ms[r][col * 2 + 1] = sb.y;
    }
    __syncthreads();
    float cr[4][4] = {}, ci[4][4] = {};
    for (int r = 0; r < 16; r++) {
        float nr[4], ni[4], mr[4], mi_[4];
        for (int i = 0; i < 4; i++) { nr[i] = Ns[r][(ty * 4 + i) * 2]; ni[i] = Ns[r][(ty * 4 + i) * 2 + 1]; }
        for (int j = 0; j < 4; j++) { mr[j] = Ms[r][(tx + j * 16) * 2]; mi_[j] = Ms[r][(tx + j * 16) * 2 + 1]; }
        for (int i = 0; i < 4; i++)
            for (int j = 0; j < 4; j++) {
                cr[i][j] += nr[i] * mr[j] - ni[i] * mi_[j];
                ci[i][j] += nr[i] * mi_[j] + ni[i] * mr[j];
            }
    }
    float mu = sStat[0], rstd = sStat[1];
    unsigned int* Bb = B2T + (size_t)b * 524288;
    for (int i = 0; i < 4; i++) {
        int n = n0 + ty * 4 + i;
        int nl = ty * 4 + i;
        for (int j = 0; j < 4; j++) {
            int m = m0 + tx + j * 16;
            float2 bs = btile[tx + j * 16][nl];     // base[m][n]
            float wr = bs.x * (1.f + (cr[i][j] - mu) * rstd);
            float wi = bs.y * (1.f + ci[i][j]);
            Bb[(size_t)(2 * n) * 512 + m]     = pack2bf(wr, -wi);
            Bb[(size_t)(2 * n + 1) * 512 + m] = pack2bf(wi, wr);
        }
    }
}

// ---------------------------------------------------------------------------
// MFMA GEMM, double-buffered single-barrier K-loop. Grid (b=8, tiles):
// batch fastest -> XCD-local per-batch operands. ntx = tiles along n.
template <int TM, int TN, bool OUT_BF16>
__global__ __launch_bounds__(256) void k_gemm(const unsigned short* __restrict__ Aall,
                                              const unsigned short* __restrict__ BTall,
                                              void* __restrict__ Call,
                                              const float* __restrict__ td,
                                              const float* __restrict__ rd,
                                              size_t a_bs, size_t bt_bs, size_t c_bs,
                                              int ngl, int ntx) {
    constexpr int K = 1024;
    constexpr int NK = K / 64;
    constexpr int IT = TM / 32, JT = TN / 32;
    constexpr int STG = (TM + TN) * 64;
    constexpr int SMC = OUT_BF16 ? TM * (TN + 8) : 0;
    constexpr int SMEMN = (2 * STG > SMC) ? 2 * STG : SMC;
    __shared__ __align__(16) unsigned short smem[SMEMN];

    const int tid = threadIdx.x;
    const int b = blockIdx.x;
    const int t = blockIdx.y;
    const int mtb = t / ntx, ntb = t - mtb * ntx;
    const unsigned short* A  = Aall  + (size_t)b * a_bs;
    const unsigned short* BT = BTall + (size_t)b * bt_bs;
    const int mBase = mtb * TM;
    const int nBase = ntb * TN;
    const int wave = tid >> 6, lane = tid & 63;
    const int wm = wave >> 1, wn = wave & 1;
    const int l15 = lane & 15, q = lane >> 4;

    f32x4 acc[IT][JT];
    for (int i = 0; i < IT; i++)
        for (int j = 0; j < JT; j++) acc[i][j] = (f32x4)0.f;

    auto stage = [&](int k0, int buf) {
        unsigned short* As = smem + buf * STG;
        unsigned short* Bs = As + TM * 64;
#pragma unroll
        for (int p = 0; p < TM / 32; p++) {
            int flat = tid + p * 256;
            int r = flat >> 3, c = flat & 7;
            int gc = (c ^ (r & 7)) << 3;
            load_lds16(A + (size_t)(mBase + r) * K + k0 + gc, &As[flat << 3]);
        }
#pragma unroll
        for (int p = 0; p < TN / 32; p++) {
            int flat = tid + p * 256;
            int r = flat >> 3, c = flat & 7;
            int gc = (c ^ (r & 7)) << 3;
            load_lds16(BT + (size_t)(nBase + r) * K + k0 + gc, &Bs[flat << 3]);
        }
    };

    stage(0, 0);
    for (int kt = 0; kt < NK; kt++) {
        __syncthreads();
        if (kt + 1 < NK) stage((kt + 1) * 64, (kt + 1) & 1);
        const unsigned short* As = smem + (kt & 1) * STG;
        const unsigned short* Bs = As + TM * 64;
#pragma unroll
        for (int ks = 0; ks < 2; ks++) {
            short8 af[IT], bfr[JT];
#pragma unroll
            for (int t2 = 0; t2 < IT; t2++) {
                int ra = wm * (TM / 2) + t2 * 16 + l15;
                int ja = (ks * 4 + q) ^ (ra & 7);
                af[t2] = *(const short8*)&As[ra * 64 + ja * 8];
            }
#pragma unroll
            for (int t2 = 0; t2 < JT; t2++) {
                int rb = wn * (TN / 2) + t2 * 16 + l15;
                int jb = (ks * 4 + q) ^ (rb & 7);
                bfr[t2] = *(const short8*)&Bs[rb * 64 + jb * 8];
            }
#pragma unroll
            for (int i = 0; i < IT; i++)
#pragma unroll
                for (int j = 0; j < JT; j++)
                    acc[i][j] = __builtin_amdgcn_mfma_f32_16x16x32_bf16(af[i], bfr[j], acc[i][j], 0, 0, 0);
        }
    }

    if constexpr (OUT_BF16) {
        __syncthreads();
        unsigned short* Cs = smem;
#pragma unroll
        for (int i = 0; i < IT; i++) {
            int row0 = wm * (TM / 2) + i * 16 + q * 4;
#pragma unroll
            for (int j = 0; j < JT; j++) {
                int col = wn * (TN / 2) + j * 16 + l15;
#pragma unroll
                for (int r = 0; r < 4; r++)
                    Cs[(row0 + r) * (TN + 8) + col] = f2bf(acc[i][j][r]);
            }
        }
        __syncthreads();
        unsigned short* C = (unsigned short*)Call + (size_t)b * c_bs;
#pragma unroll
        for (int p = 0; p < TM * TN / 2048; p++) {
            int flat = tid + p * 256;
            int r = flat / (TN / 8), c = flat % (TN / 8);
            short8 v = *(const short8*)&Cs[r * (TN + 8) + c * 8];
            *(short8*)(C + (size_t)(mBase + r) * ngl + nBase + c * 8) = v;
        }
    } else {
        float CC = 0.f;
        for (int c = 0; c < 16; c++) CC += td[2 * c + 1] * rd[2 * c + 1] - td[2 * c] * rd[2 * c];
        float* C = (float*)Call + (size_t)b * c_bs;
#pragma unroll
        for (int i = 0; i < IT; i++) {
            int row0 = mBase + wm * (TM / 2) + i * 16 + q * 4;
#pragma unroll
            for (int j = 0; j < JT; j++) {
                int col = nBase + wn * (TN / 2) + j * 16 + l15;
#pragma unroll
                for (int r = 0; r < 4; r++)
                    C[(size_t)(row0 + r) * ngl + col] = acc[i][j][r] + CC;
            }
        }
    }
}

// ---------------------------------------------------------------------------
extern "C" void kernel_launch(void* const* d_in, const int* in_sizes, int n_in,
                              void* d_out, int out_size, void* d_ws, size_t ws_size,
                              hipStream_t stream) {
    const float* x    = (const float*)d_in[0];
    const float* Wi   = (const float*)d_in[1];
    const float* Wj   = (const float*)d_in[2];
    const float* base = (const float*)d_in[3];
    const float* td   = (const float*)d_in[6];
    const float* rd   = (const float*)d_in[7];
    const float* modi = (const float*)d_in[8];
    const float* modj = (const float*)d_in[9];
    const float* inv  = (const float*)d_in[10];
    const float* mt   = (const float*)d_in[11];
    float* ws  = (float*)d_ws;
    float* out = (float*)d_out;

    unsigned short* A2  = (unsigned short*)(ws + WS_A2);
    unsigned short* B5T = (unsigned short*)(ws + WS_B5T);
    unsigned short* B2T = (unsigned short*)(ws + WS_B2T);
    unsigned short* G1X = (unsigned short*)(ws + WS_G1X);

    k_front<<<768, 256, 0, stream>>>(Wi, Wj, rd, x, mt, inv, modi, modj, ws);
    k_bmod<<<dim3(8, 64), 256, 0, stream>>>(base, ws);
    k_gemm<128, 64, true><<<dim3(8, 64), 256, 0, stream>>>(
        A2, B2T, (void*)G1X, td, rd, (size_t)0, (size_t)1048576, (size_t)524288, 1024, 16);
    k_gemm<64, 128, false><<<dim3(8, 32), 256, 0, stream>>>(
        G1X, B5T, (void*)out, td, rd, (size_t)524288, (size_t)0, (size_t)262144, 512, 4);
}